// Round 7
// baseline (279.283 us; speedup 1.0000x reference)
//
#include <hip/hip_runtime.h>
#include <hip/hip_bf16.h>

typedef unsigned short u16;
typedef __attribute__((ext_vector_type(8))) short short8;
typedef __attribute__((ext_vector_type(4))) short short4_t;
typedef __attribute__((ext_vector_type(4))) float f32x4;

#define MFMA16(a, b, c) __builtin_amdgcn_mfma_f32_16x16x32_bf16((a), (b), (c), 0, 0, 0)

#if __has_builtin(__builtin_amdgcn_mfma_f32_16x16x16bf16_1k)
#define MFMAK16(a, b, c) __builtin_amdgcn_mfma_f32_16x16x16bf16_1k((a), (b), (c), 0, 0, 0)
#elif __has_builtin(__builtin_amdgcn_mfma_f32_16x16x16_bf16)
#define MFMAK16(a, b, c) __builtin_amdgcn_mfma_f32_16x16x16_bf16((a), (b), (c), 0, 0, 0)
#else
__device__ __forceinline__ f32x4 mfmak16_asm(short4_t a, short4_t b, f32x4 c) {
  asm("v_mfma_f32_16x16x16_bf16 %0, %1, %2, %0" : "+v"(c) : "v"(a), "v"(b));
  return c;
}
#define MFMAK16(a, b, c) mfmak16_asm((a), (b), (c))
#endif

#define GLOAD_LDS16(gp, lp)                                          \
  __builtin_amdgcn_global_load_lds(                                  \
      (const __attribute__((address_space(1))) void*)(gp),           \
      (__attribute__((address_space(3))) void*)(lp), 16, 0, 0)
#define SBAR() asm volatile("s_barrier" ::: "memory")
#define WAIT_LGKM0() asm volatile("s_waitcnt lgkmcnt(0)" ::: "memory")
#define WAIT_VM0() asm volatile("s_waitcnt vmcnt(0)" ::: "memory")

#define LOG2E 1.44269504088896340736f

__device__ __forceinline__ float us2f(u16 u) {
  union { unsigned int i; float f; } c; c.i = ((unsigned int)u) << 16; return c.f;
}
__device__ __forceinline__ u16 f2us(float f) {
  union { float f; unsigned int i; } c; c.f = f;
  return (u16)((c.i + 0x7fffu + ((c.i >> 16) & 1u)) >> 16);
}
__device__ __forceinline__ unsigned int f2us2(float a, float b) {
  union { __hip_bfloat162 h; unsigned int u; } c;
  c.h = __float22bfloat162_rn(float2{a, b});
  return c.u;
}
__device__ __forceinline__ float exp2fast(float x) {
#if __has_builtin(__builtin_amdgcn_exp2f)
  return __builtin_amdgcn_exp2f(x);
#else
  return exp2f(x);
#endif
}

// ---------------------------------------------------------------------------
// GEMM: Y = (X @ W^T + bias) * oscale.  BM x BN block tile, 4 waves (2x2).
// MODE 0: f32 row-major [4096][1024].  MODE 1: u16 [bh][s][d].  MODE 2:
// u16 [bh][d][s].  Modes 1/2 (BM=BN=128 only) write through an LDS transpose.
// AF32/BF32: operand is f32 in global; converted to bf16 during reg-staging
// (global f32 -> VGPR -> cvt -> swizzled ds_write). Replaces the separate
// cvt pass entirely (L3 absorbs the f32 re-reads).
// ---------------------------------------------------------------------------
template <int MODE, typename OUT, int BM, int BN, bool AF32, bool BF32>
__device__ __forceinline__ void gemm_body(u16* __restrict__ SM,
                                          const void* __restrict__ Xp,
                                          const void* __restrict__ Wp,
                                          const float* __restrict__ bias,
                                          OUT* __restrict__ Y, int row0, int col0,
                                          float oscale) {
  constexpr int TM = BM / 32, TN = BN / 32;  // 8-row groups per wave
  u16* As = SM;              // [BM][64]
  u16* Bs = SM + BM * 64;    // [BN][64]
  const int tid = threadIdx.x;
  const int lane = tid & 63;
  const int wid = tid >> 6;
  const int wm = wid >> 1, wn = wid & 1;
  const int l15 = lane & 15, l16 = lane >> 4;
  const int lrow = lane >> 3;              // row within 8-row group
  const int lchunk = (lane & 7) ^ lrow;    // pre-swizzled source chunk (gload)
  const int schunk = lane & 7;             // chunk for reg-staging path

  // stage one 8-row group from f32 source into bf16 tile w/ XOR swizzle
  auto stage8f = [&](u16* dst, const float* src, int trow) {
    const float* p = src + schunk * 8;
    const float4 a = *(const float4*)p;
    const float4 b2 = *(const float4*)(p + 4);
    unsigned int o[4];
    o[0] = f2us2(a.x, a.y); o[1] = f2us2(a.z, a.w);
    o[2] = f2us2(b2.x, b2.y); o[3] = f2us2(b2.z, b2.w);
    *(short8*)&dst[trow * 64 + ((schunk ^ (trow & 7)) * 8)] = *(short8*)o;
  };

  f32x4 acc[TM][TN];
#pragma unroll
  for (int i = 0; i < TM; i++)
#pragma unroll
    for (int j = 0; j < TN; j++) acc[i][j] = (f32x4){0.f, 0.f, 0.f, 0.f};

  for (int k0 = 0; k0 < 1024; k0 += 64) {
    if constexpr (AF32) {
      const float* X = (const float*)Xp;
#pragma unroll
      for (int i = 0; i < TM; i++) {
        const int rb = (wid * TM + i) * 8 + lrow;
        stage8f(As, X + (size_t)(row0 + rb) * 1024 + k0, rb);
      }
    } else {
      const u16* X = (const u16*)Xp;
#pragma unroll
      for (int i = 0; i < TM; i++) {
        const int rb = (wid * TM + i) * 8;
        GLOAD_LDS16(X + (size_t)(row0 + rb + lrow) * 1024 + k0 + lchunk * 8, &As[rb * 64]);
      }
    }
    if constexpr (BF32) {
      const float* W = (const float*)Wp;
#pragma unroll
      for (int i = 0; i < TN; i++) {
        const int rb = (wid * TN + i) * 8 + lrow;
        stage8f(Bs, W + (size_t)(col0 + rb) * 1024 + k0, rb);
      }
    } else {
      const u16* W = (const u16*)Wp;
#pragma unroll
      for (int i = 0; i < TN; i++) {
        const int rb = (wid * TN + i) * 8;
        GLOAD_LDS16(W + (size_t)(col0 + rb + lrow) * 1024 + k0 + lchunk * 8, &Bs[rb * 64]);
      }
    }
    __syncthreads();
#pragma unroll
    for (int kk = 0; kk < 2; kk++) {
      const int ch = kk * 4 + l16;
      short8 af[TM], bfr[TN];
#pragma unroll
      for (int t = 0; t < TM; t++) {
        const int m = wm * (BM / 2) + t * 16 + l15;
        af[t] = *(const short8*)&As[m * 64 + ((ch ^ (m & 7)) * 8)];
      }
#pragma unroll
      for (int t = 0; t < TN; t++) {
        const int n = wn * (BN / 2) + t * 16 + l15;
        bfr[t] = *(const short8*)&Bs[n * 64 + ((ch ^ (n & 7)) * 8)];
      }
#pragma unroll
      for (int tm = 0; tm < TM; tm++)
#pragma unroll
        for (int tn = 0; tn < TN; tn++)
          acc[tm][tn] = MFMA16(af[tm], bfr[tn], acc[tm][tn]);
    }
    __syncthreads();
  }

  if (MODE == 0) {
#pragma unroll
    for (int tn = 0; tn < TN; tn++) {
      const int col = col0 + wn * (BN / 2) + tn * 16 + l15;
      const float bv = bias[col];
#pragma unroll
      for (int tm = 0; tm < TM; tm++) {
        const int rowb = row0 + wm * (BM / 2) + tm * 16 + l16 * 4;
#pragma unroll
        for (int r = 0; r < 4; r++)
          Y[(size_t)(rowb + r) * 1024 + col] = (OUT)(acc[tm][tn][r] + bv);
      }
    }
  } else {
    // LDS-transpose epilogue (BM=BN=128 only), two 64-row passes.
    u16* T = SM;
    const int bb = row0 >> 11;
    const int sbase = row0 & 2047;
#pragma unroll
    for (int pass = 0; pass < 2; pass++) {
      __syncthreads();
      if (wm == pass) {
#pragma unroll
        for (int tn = 0; tn < TN; tn++) {
          const int coll = wn * 64 + tn * 16 + l15;
          const float bv = bias[col0 + coll];
#pragma unroll
          for (int tm = 0; tm < TM; tm++) {
            if (MODE == 1) {
#pragma unroll
              for (int r = 0; r < 4; r++)
                T[(tm * 16 + l16 * 4 + r) * 136 + coll] = f2us((acc[tm][tn][r] + bv) * oscale);
            } else {
              unsigned int o[2];
              o[0] = f2us2(acc[tm][tn][0] + bv, acc[tm][tn][1] + bv);
              o[1] = f2us2(acc[tm][tn][2] + bv, acc[tm][tn][3] + bv);
              *(short4_t*)&T[coll * 72 + tm * 16 + l16 * 4] = *(short4_t*)o;
            }
          }
        }
      }
      __syncthreads();
      if (MODE == 1) {
#pragma unroll
        for (int i = 0; i < 8; i++) {
          const int idx = tid + i * 256;           // 2048 chunks of 4 u16
          const int srow = idx >> 5, c4 = idx & 31;
          const short4_t v = *(const short4_t*)&T[srow * 136 + c4 * 4];
          const int col = col0 + c4 * 4;
          const int hh = col >> 6, dd = col & 63;
          const int s = sbase + pass * 64 + srow;
          *(short4_t*)&((u16*)Y)[(((size_t)(bb * 16 + hh)) * 2048 + s) * 64 + dd] = v;
        }
      } else {
#pragma unroll
        for (int i = 0; i < 4; i++) {
          const int idx = tid + i * 256;           // 1024 chunks of 8 u16
          const int cl = idx >> 3, sc = idx & 7;
          const short8 v = *(const short8*)&T[cl * 72 + sc * 8];
          const int col = col0 + cl;
          const int hh = col >> 6, dd = col & 63;
          const int s = sbase + pass * 64 + sc * 8;
          *(short8*)&((u16*)Y)[(((size_t)(bb * 16 + hh)) * 64 + dd) * 2048 + s] = v;
        }
      }
    }
  }
}

// qkv: reads f32 query/key/value and f32 weights directly (fused conversion).
__global__ __launch_bounds__(256) void qkv_kernel(
    const float* Xq, const float* Xk, const float* Xv, const float* Wq,
    const float* Wk, const float* Wv, const float* bq, const float* bk,
    const float* bv, u16* Yq, u16* Yk, u16* Yv) {
  __shared__ __align__(16) u16 SM[16384];
  const int z = blockIdx.z;
  const float* X = z == 0 ? Xq : (z == 1 ? Xk : Xv);
  const float* W = z == 0 ? Wq : (z == 1 ? Wk : Wv);
  const float* bi = z == 0 ? bq : (z == 1 ? bk : bv);
  u16* Y = z == 0 ? Yq : (z == 1 ? Yk : Yv);
  if (z == 2)
    gemm_body<2, u16, 128, 128, true, true>(SM, X, W, bi, Y, blockIdx.x * 128,
                                            blockIdx.y * 128, 1.0f);
  else
    gemm_body<1, u16, 128, 128, true, true>(SM, X, W, bi, Y, blockIdx.x * 128,
                                            blockIdx.y * 128,
                                            z == 0 ? LOG2E : 1.0f);
}

// oproj: ctx bf16 (gload_lds) x Wo f32 (fused conversion); 64x64 tiles, 4/CU.
__global__ __launch_bounds__(256) void oproj_kernel(const u16* Xc, const float* Wo,
                                                    const float* bo, float* out) {
  __shared__ __align__(16) u16 SM[8192];
  gemm_body<0, float, 64, 64, false, true>(SM, Xc, Wo, bo, out, blockIdx.x * 64,
                                           blockIdx.y * 64, 1.0f);
}

// ---------------------------------------------------------------------------
// Flash attention (S^T trick, rel-pos). r15 = r12 attn verbatim (74.4 µs,
// best verified; the padded-V experiment r13/r14 cost more than the 2-way
// conflicts it removed — m136: 2-way is ~free) with one change: the qrel
// GEMM converts the tiny relk table f32->bf16 in-register (rows >=33 zeroed
// by predicate), eliminating the cvt_relk kernel and the relkb buffer.
// ---------------------------------------------------------------------------
__global__ __launch_bounds__(256, 6) void attn_kernel(
    const u16* __restrict__ Qg, const u16* __restrict__ Kg,
    const u16* __restrict__ Vtg, const float* __restrict__ relk,
    const float* __restrict__ relv, u16* __restrict__ ctx) {
  __shared__ __align__(16) u16 KV[8192];       // K [0,4096), V^T [4096,8192)
  __shared__ __align__(16) u16 qrelJ[64 * 33]; // Q[q]·relk[j] bf16
  __shared__ __align__(16) u16 wsum[64 * 32];  // in-band p, write-once, col31=0

  const int tid = threadIdx.x, lane = tid & 63, wid = tid >> 6;
  const int l15 = lane & 15, l16 = lane >> 4;
  const int bh = blockIdx.x;  // x-fast => all q-tiles of a bh land on one XCD
  const int b = bh >> 4, h = bh & 15;
  const int by = blockIdx.y;
  const int q0 = by * 64;
  const u16* Qb = Qg + (size_t)bh * 2048 * 64;
  const u16* Kb = Kg + (size_t)bh * 2048 * 64;
  const u16* Vtb = Vtg + (size_t)bh * 64 * 2048;  // [d][s]

  const int lrow = lane >> 3;
  const int lchunk = (lane & 7) ^ lrow;
  const int qw = wid * 16;
  const int kq4 = l16 * 4;
  const int qrow = qw + l15;

  // ---- prologue: stage Q into KV, zero wsum ----
#pragma unroll
  for (int i = 0; i < 2; i++) {
    const int rb = qw + i * 8;
    GLOAD_LDS16(Qb + (size_t)(q0 + rb + lrow) * 64 + lchunk * 8, &KV[rb * 64]);
  }
  for (int idx = tid; idx < 1024; idx += 256) ((unsigned int*)wsum)[idx] = 0u;
  __syncthreads();

  // ---- hoist Q fragment ----
  short8 aq[2];
  {
    const int m = qw + l15;
    aq[0] = *(const short8*)&KV[m * 64 + ((l16 ^ (m & 7)) * 8)];
    aq[1] = *(const short8*)&KV[m * 64 + (((4 + l16) ^ (m & 7)) * 8)];
  }
  // ---- qrel GEMM: qrelJ[q][j] = Q[q]·relk[j]; relk f32 cvt in-reg ----
  {
    f32x4 qa[3];
#pragma unroll
    for (int nt = 0; nt < 3; nt++) {
      qa[nt] = (f32x4){0.f, 0.f, 0.f, 0.f};
#pragma unroll
      for (int kk = 0; kk < 2; kk++) {
        const int rr = nt * 16 + l15;  // relk row; valid rows 0..32
        short8 bf;
        if (rr < 33) {
          const float* p = relk + rr * 64 + kk * 32 + l16 * 8;
          const float4 a = *(const float4*)p;
          const float4 b2 = *(const float4*)(p + 4);
          unsigned int o[4];
          o[0] = f2us2(a.x, a.y); o[1] = f2us2(a.z, a.w);
          o[2] = f2us2(b2.x, b2.y); o[3] = f2us2(b2.z, b2.w);
          bf = *(short8*)o;
        } else {
          bf = (short8){0, 0, 0, 0, 0, 0, 0, 0};
        }
        qa[nt] = MFMA16(aq[kk], bf, qa[nt]);
      }
    }
#pragma unroll
    for (int nt = 0; nt < 3; nt++) {
      if (nt < 2 || l15 == 0) {
#pragma unroll
        for (int r = 0; r < 4; r++)
          qrelJ[(qw + kq4 + r) * 33 + nt * 16 + l15] = f2us(qa[nt][r]);
      }
    }
  }
  WAIT_LGKM0();  // aq reads + qrelJ writes drained before KV overwrite / reads
  const float q0r = us2f(qrelJ[qrow * 33 + 0]);
  const float q32r = us2f(qrelJ[qrow * 33 + 32]);
  const f32x4 ebl = (f32x4){q0r, q0r, q0r, q0r};
  const f32x4 ebr = (f32x4){q32r, q32r, q32r, q32r};
  const f32x4 zf = (f32x4){0.f, 0.f, 0.f, 0.f};
  const short4_t ones4 = (short4_t){(short)0x3F80, (short)0x3F80,
                                    (short)0x3F80, (short)0x3F80};

  float wl_p = 0.f, wr_p = 0.f;            // diag-tile partials (VALU)
  f32x4 SL = zf, SR = zf, SD = zf;         // ones-MFMA denominator sums
  f32x4 Oacc[4];
#pragma unroll
  for (int t = 0; t < 4; t++) Oacc[t] = zf;

  // stage K/V tile k0c into LDS (single buffer, two barriers)
  auto stage = [&](int k0c) {
    SBAR();  // all waves done reading previous tile
#pragma unroll
    for (int i = 0; i < 2; i++) {
      const int rb = qw + i * 8;
      GLOAD_LDS16(Kb + (size_t)(k0c + rb + lrow) * 64 + lchunk * 8, &KV[rb * 64]);
    }
#pragma unroll
    for (int i = 0; i < 2; i++) {
      const int rb = qw + i * 8;
      GLOAD_LDS16(Vtb + (size_t)(rb + lrow) * 2048 + k0c + lchunk * 8,
                  &KV[4096 + rb * 64]);
    }
    WAIT_VM0();
    SBAR();  // tile visible to all waves
  };

  // S^T quadrant tn = K·Q^T with C-init (bias pre-folded for off-diag)
  auto qk = [&](int tn, f32x4 cin) -> f32x4 {
    const int n = tn * 16 + l15;
    const short8 bk0 = *(const short8*)&KV[n * 64 + ((l16 ^ (n & 7)) * 8)];
    const short8 bk1 = *(const short8*)&KV[n * 64 + (((4 + l16) ^ (n & 7)) * 8)];
    f32x4 s = MFMA16(bk0, aq[0], cin);
    s = MFMA16(bk1, aq[1], s);
    return s;
  };

  // O^T += V^T · P^T
  auto pvstep = [&](const short4_t* pf) {
    __builtin_amdgcn_s_setprio(1);
#pragma unroll
    for (int td = 0; td < 4; td++) {
      const int row = td * 16 + l15;
      const int rs = row & 7;
#pragma unroll
      for (int kk = 0; kk < 4; kk++) {
        const short4_t vf = *(const short4_t*)&KV[4096 + row * 64 +
                                                  (((kk * 2 + (l16 >> 1)) ^ rs) * 8) +
                                                  (l16 & 1) * 4];
        Oacc[td] = MFMAK16(vf, pf[kk], Oacc[td]);
      }
    }
    __builtin_amdgcn_s_setprio(0);
  };

  // denominator: S += colsum(P) via ones-row MFMA (matrix pipe, no VALU)
  auto psum = [&](const short4_t* pf, f32x4& S) {
#pragma unroll
    for (int kk = 0; kk < 4; kk++) S = MFMAK16(ones4, pf[kk], S);
  };

  // off-diagonal tile body: bias folded into C, no per-score bookkeeping
  auto offdiag = [&](f32x4 ebv, f32x4& S) {
    short4_t pf[4];
#pragma unroll
    for (int tn = 0; tn < 4; tn++) {
      const f32x4 sac = qk(tn, ebv);
      union { unsigned int u[2]; short4_t s; } c;
      c.u[0] = f2us2(exp2fast(sac[0]), exp2fast(sac[1]));
      c.u[1] = f2us2(exp2fast(sac[2]), exp2fast(sac[3]));
      pf[tn] = c.s;
    }
    pvstep(pf);
    psum(pf, S);
  };

  // diagonal tile body: per-element clamp/bias, in-band p to wsum
  auto diag = [&](int k0) {
    short4_t pf[4];
#pragma unroll
    for (int tn = 0; tn < 4; tn++) {
      const f32x4 sac = qk(tn, zf);
      float pv4[4];
#pragma unroll
      for (int r = 0; r < 4; r++) {
        const int kg = k0 + tn * 16 + kq4 + r;
        const int dlt = kg - (q0 + qrow);
        const int jj = (dlt < -16 ? -16 : (dlt > 16 ? 16 : dlt)) + 16;
        const float p = exp2fast(sac[r] + us2f(qrelJ[qrow * 33 + jj]));
        pv4[r] = p;
        if (dlt <= -16) wl_p += p;
        else if (dlt >= 16) wr_p += p;
        else wsum[qrow * 32 + (dlt + 15)] = f2us(p);
      }
      union { unsigned int u[2]; short4_t s; } c;
      c.u[0] = f2us2(pv4[0], pv4[1]);
      c.u[1] = f2us2(pv4[2], pv4[3]);
      pf[tn] = c.s;
    }
    pvstep(pf);
    psum(pf, SD);
  };

  // ---- main loop, split into left / diag / right tile ranges ----
  const int dlo = (by >= 1) ? by - 1 : 0;        // first diag tile
  const int dhi = (by + 2 <= 32) ? by + 2 : 32;  // one past last diag tile
  for (int kt = 0; kt < dlo; ++kt) { stage(kt * 64); offdiag(ebl, SL); }
  for (int kt = dlo; kt < dhi; ++kt) { stage(kt * 64); diag(kt * 64); }
  for (int kt = dhi; kt < 32; ++kt) { stage(kt * 64); offdiag(ebr, SR); }

  // ---- epilogue ----
  wl_p += __shfl_xor(wl_p, 16); wl_p += __shfl_xor(wl_p, 32);
  wr_p += __shfl_xor(wr_p, 16); wr_p += __shfl_xor(wr_p, 32);
  const float l_total = SL[0] + SR[0] + SD[0];   // full col sums, no shuffle
  const float linv = 1.f / l_total;
  const float wl = (SL[0] + wl_p) * linv;
  const float wr = (SR[0] + wr_p) * linv;

  // rel_v in-band term as a matmul: O^T[d][q] += sum_c relv[c+1][d]*wsum[q][c]
  {
    short4_t relf[4][2];  // A: rows d=td*16+l15, k = kk*16 + l16*4 + e
#pragma unroll
    for (int td = 0; td < 4; td++)
#pragma unroll
      for (int kk = 0; kk < 2; kk++) {
        const int jb = kk * 16 + l16 * 4 + 1;  // relv rows 1..32, all valid
        const int d = td * 16 + l15;
        union { unsigned int u[2]; short4_t s; } c;
        c.u[0] = f2us2(relv[(jb + 0) * 64 + d], relv[(jb + 1) * 64 + d]);
        c.u[1] = f2us2(relv[(jb + 2) * 64 + d], relv[(jb + 3) * 64 + d]);
        relf[td][kk] = c.s;
      }
    WAIT_LGKM0();  // wave's own wsum ds_writes drained before re-read
    short4_t wfrag[2];    // B: col q=qw+l15, k = kk*16 + l16*4 + e (col31=0)
#pragma unroll
    for (int kk = 0; kk < 2; kk++)
      wfrag[kk] = *(const short4_t*)&wsum[qrow * 32 + kk * 16 + l16 * 4];
#pragma unroll
    for (int td = 0; td < 4; td++)
#pragma unroll
      for (int kk = 0; kk < 2; kk++)
        Oacc[td] = MFMAK16(relf[td][kk], wfrag[kk], Oacc[td]);
  }

#pragma unroll
  for (int td = 0; td < 4; td++) {
    const f32x4 rv0 = *(const f32x4*)&relv[td * 16 + kq4];
    const f32x4 rv32 = *(const f32x4*)&relv[32 * 64 + td * 16 + kq4];
#pragma unroll
    for (int r = 0; r < 4; r++)
      Oacc[td][r] = Oacc[td][r] * linv + wl * rv0[r] + wr * rv32[r];
  }

  SBAR();  // all waves past their last KV reads -> KV free for O tile
  // O tile [q 64][d 64] stride 72 u16 (b128-aligned), wave-private q rows
#pragma unroll
  for (int td = 0; td < 4; td++) {
    unsigned int o[2];
    o[0] = f2us2(Oacc[td][0], Oacc[td][1]);
    o[1] = f2us2(Oacc[td][2], Oacc[td][3]);
    *(short4_t*)&KV[qrow * 72 + td * 16 + kq4] = *(short4_t*)o;
  }
  WAIT_LGKM0();
  SBAR();
#pragma unroll
  for (int i = 0; i < 2; i++) {
    const int idx = tid + i * 256;  // 512 chunks of 8 u16
    const int q = idx >> 3, sc = idx & 7;
    const short8 v = *(const short8*)&KV[q * 72 + sc * 8];
    *(short8*)&ctx[((size_t)b * 2048 + q0 + q) * 1024 + h * 64 + sc * 8] = v;
  }
}

// ---------------------------------------------------------------------------
extern "C" void kernel_launch(void* const* d_in, const int* in_sizes, int n_in,
                              void* d_out, int out_size, void* d_ws, size_t ws_size,
                              hipStream_t stream) {
  u16* qb = (u16*)d_ws;                 // [32][2048][64]
  u16* kb = qb + 4194304;               // [32][2048][64]
  u16* vtb = kb + 4194304;              // [32][64][2048]
  u16* ctx = vtb + 4194304;             // [2][2048][1024]

  const float* query = (const float*)d_in[0];
  const float* key = (const float*)d_in[1];
  const float* value = (const float*)d_in[2];
  const float* Wq = (const float*)d_in[3];
  const float* bq = (const float*)d_in[4];
  const float* Wk = (const float*)d_in[5];
  const float* bk = (const float*)d_in[6];
  const float* Wv = (const float*)d_in[7];
  const float* bv = (const float*)d_in[8];
  const float* Wo = (const float*)d_in[9];
  const float* bo = (const float*)d_in[10];
  const float* relk = (const float*)d_in[11];
  const float* relv = (const float*)d_in[12];

  dim3 blk(256);
  qkv_kernel<<<dim3(32, 8, 3), blk, 0, stream>>>(query, key, value, Wq, Wk, Wv,
                                                 bq, bk, bv, qb, kb, vtb);
  attn_kernel<<<dim3(32, 32), blk, 0, stream>>>(qb, kb, vtb, relk, relv, ctx);
  oproj_kernel<<<dim3(64, 16), blk, 0, stream>>>(ctx, Wo, bo, (float*)d_out);
}

// Round 8
// 254.789 us; speedup vs baseline: 1.0961x; 1.0961x over previous
//
#include <hip/hip_runtime.h>
#include <hip/hip_bf16.h>

typedef unsigned short u16;
typedef __attribute__((ext_vector_type(8))) short short8;
typedef __attribute__((ext_vector_type(4))) short short4_t;
typedef __attribute__((ext_vector_type(4))) float f32x4;

#define MFMA16(a, b, c) __builtin_amdgcn_mfma_f32_16x16x32_bf16((a), (b), (c), 0, 0, 0)

#if __has_builtin(__builtin_amdgcn_mfma_f32_16x16x16bf16_1k)
#define MFMAK16(a, b, c) __builtin_amdgcn_mfma_f32_16x16x16bf16_1k((a), (b), (c), 0, 0, 0)
#elif __has_builtin(__builtin_amdgcn_mfma_f32_16x16x16_bf16)
#define MFMAK16(a, b, c) __builtin_amdgcn_mfma_f32_16x16x16_bf16((a), (b), (c), 0, 0, 0)
#else
__device__ __forceinline__ f32x4 mfmak16_asm(short4_t a, short4_t b, f32x4 c) {
  asm("v_mfma_f32_16x16x16_bf16 %0, %1, %2, %0" : "+v"(c) : "v"(a), "v"(b));
  return c;
}
#define MFMAK16(a, b, c) mfmak16_asm((a), (b), (c))
#endif

#define GLOAD_LDS16(gp, lp)                                          \
  __builtin_amdgcn_global_load_lds(                                  \
      (const __attribute__((address_space(1))) void*)(gp),           \
      (__attribute__((address_space(3))) void*)(lp), 16, 0, 0)
#define SBAR() asm volatile("s_barrier" ::: "memory")
#define WAIT_LGKM0() asm volatile("s_waitcnt lgkmcnt(0)" ::: "memory")
#define WAIT_VM0() asm volatile("s_waitcnt vmcnt(0)" ::: "memory")

#define LOG2E 1.44269504088896340736f

__device__ __forceinline__ float us2f(u16 u) {
  union { unsigned int i; float f; } c; c.i = ((unsigned int)u) << 16; return c.f;
}
__device__ __forceinline__ u16 f2us(float f) {
  union { float f; unsigned int i; } c; c.f = f;
  return (u16)((c.i + 0x7fffu + ((c.i >> 16) & 1u)) >> 16);
}
__device__ __forceinline__ unsigned int f2us2(float a, float b) {
  union { __hip_bfloat162 h; unsigned int u; } c;
  c.h = __float22bfloat162_rn(float2{a, b});
  return c.u;
}
__device__ __forceinline__ float exp2fast(float x) {
#if __has_builtin(__builtin_amdgcn_exp2f)
  return __builtin_amdgcn_exp2f(x);
#else
  return exp2f(x);
#endif
}

// ---------------------------------------------------------------------------
// Fused f32 -> bf16 convert for the 7 big tensors (3 inputs + 4 weights).
// The separate pass reads the f32 data ONCE at streaming BW; the GEMMs then
// read half the bytes via async global_load_lds. (r15 showed in-GEMM f32
// fusion is latency-bound and re-fetches panels from HBM: qkv 74 -> 87 µs.)
// ---------------------------------------------------------------------------
__global__ __launch_bounds__(256) void cvt_all_kernel(
    const float* x0, const float* x1, const float* x2, const float* w0,
    const float* w1, const float* w2, const float* w3, u16* y0, u16* y1,
    u16* y2, u16* z0, u16* z1, u16* z2, u16* z3) {
  const int z = blockIdx.z;
  const float* src; u16* dst; int n;
  switch (z) {
    case 0: src = x0; dst = y0; n = 4194304; break;
    case 1: src = x1; dst = y1; n = 4194304; break;
    case 2: src = x2; dst = y2; n = 4194304; break;
    case 3: src = w0; dst = z0; n = 1048576; break;
    case 4: src = w1; dst = z1; n = 1048576; break;
    case 5: src = w2; dst = z2; n = 1048576; break;
    default: src = w3; dst = z3; n = 1048576; break;
  }
  const int i = (blockIdx.x * 256 + threadIdx.x) * 8;
  if (i < n) {
    const float4 a = *(const float4*)(src + i);
    const float4 b = *(const float4*)(src + i + 4);
    unsigned int o[4];
    o[0] = f2us2(a.x, a.y); o[1] = f2us2(a.z, a.w);
    o[2] = f2us2(b.x, b.y); o[3] = f2us2(b.z, b.w);
    *(uint4*)(dst + i) = *(uint4*)o;
  }
}

// ---------------------------------------------------------------------------
// GEMM: Y = (X @ W^T + bias) * oscale.  BM x BN block tile, 4 waves (2x2).
// MODE 0: f32 row-major [4096][1024].  MODE 1: u16 [bh][s][d].  MODE 2:
// u16 [bh][d][s].  Modes 1/2 (BM=BN=128 only) write through an LDS transpose.
// ---------------------------------------------------------------------------
template <int MODE, typename OUT, int BM, int BN>
__device__ __forceinline__ void gemm_body(u16* __restrict__ SM,
                                          const u16* __restrict__ X,
                                          const u16* __restrict__ W,
                                          const float* __restrict__ bias,
                                          OUT* __restrict__ Y, int row0, int col0,
                                          float oscale) {
  constexpr int TM = BM / 32, TN = BN / 32;  // 16-row tiles per wave
  u16* As = SM;              // [BM][64]
  u16* Bs = SM + BM * 64;    // [BN][64]
  const int tid = threadIdx.x;
  const int lane = tid & 63;
  const int wid = tid >> 6;
  const int wm = wid >> 1, wn = wid & 1;
  const int l15 = lane & 15, l16 = lane >> 4;
  const int lrow = lane >> 3;
  const int lchunk = (lane & 7) ^ lrow;

  f32x4 acc[TM][TN];
#pragma unroll
  for (int i = 0; i < TM; i++)
#pragma unroll
    for (int j = 0; j < TN; j++) acc[i][j] = (f32x4){0.f, 0.f, 0.f, 0.f};

  for (int k0 = 0; k0 < 1024; k0 += 64) {
#pragma unroll
    for (int i = 0; i < TM; i++) {
      const int rb = (wid * TM + i) * 8;
      GLOAD_LDS16(X + (size_t)(row0 + rb + lrow) * 1024 + k0 + lchunk * 8, &As[rb * 64]);
    }
#pragma unroll
    for (int i = 0; i < TN; i++) {
      const int rb = (wid * TN + i) * 8;
      GLOAD_LDS16(W + (size_t)(col0 + rb + lrow) * 1024 + k0 + lchunk * 8, &Bs[rb * 64]);
    }
    __syncthreads();
#pragma unroll
    for (int kk = 0; kk < 2; kk++) {
      const int ch = kk * 4 + l16;
      short8 af[TM], bfr[TN];
#pragma unroll
      for (int t = 0; t < TM; t++) {
        const int m = wm * (BM / 2) + t * 16 + l15;
        af[t] = *(const short8*)&As[m * 64 + ((ch ^ (m & 7)) * 8)];
      }
#pragma unroll
      for (int t = 0; t < TN; t++) {
        const int n = wn * (BN / 2) + t * 16 + l15;
        bfr[t] = *(const short8*)&Bs[n * 64 + ((ch ^ (n & 7)) * 8)];
      }
#pragma unroll
      for (int tm = 0; tm < TM; tm++)
#pragma unroll
        for (int tn = 0; tn < TN; tn++)
          acc[tm][tn] = MFMA16(af[tm], bfr[tn], acc[tm][tn]);
    }
    __syncthreads();
  }

  if (MODE == 0) {
#pragma unroll
    for (int tn = 0; tn < TN; tn++) {
      const int col = col0 + wn * (BN / 2) + tn * 16 + l15;
      const float bv = bias[col];
#pragma unroll
      for (int tm = 0; tm < TM; tm++) {
        const int rowb = row0 + wm * (BM / 2) + tm * 16 + l16 * 4;
#pragma unroll
        for (int r = 0; r < 4; r++)
          Y[(size_t)(rowb + r) * 1024 + col] = (OUT)(acc[tm][tn][r] + bv);
      }
    }
  } else {
    // LDS-transpose epilogue (BM=BN=128 only), two 64-row passes.
    u16* T = SM;
    const int bb = row0 >> 11;
    const int sbase = row0 & 2047;
#pragma unroll
    for (int pass = 0; pass < 2; pass++) {
      __syncthreads();
      if (wm == pass) {
#pragma unroll
        for (int tn = 0; tn < TN; tn++) {
          const int coll = wn * 64 + tn * 16 + l15;
          const float bv = bias[col0 + coll];
#pragma unroll
          for (int tm = 0; tm < TM; tm++) {
            if (MODE == 1) {
#pragma unroll
              for (int r = 0; r < 4; r++)
                T[(tm * 16 + l16 * 4 + r) * 136 + coll] = f2us((acc[tm][tn][r] + bv) * oscale);
            } else {
              unsigned int o[2];
              o[0] = f2us2(acc[tm][tn][0] + bv, acc[tm][tn][1] + bv);
              o[1] = f2us2(acc[tm][tn][2] + bv, acc[tm][tn][3] + bv);
              *(short4_t*)&T[coll * 72 + tm * 16 + l16 * 4] = *(short4_t*)o;
            }
          }
        }
      }
      __syncthreads();
      if (MODE == 1) {
#pragma unroll
        for (int i = 0; i < 8; i++) {
          const int idx = tid + i * 256;           // 2048 chunks of 4 u16
          const int srow = idx >> 5, c4 = idx & 31;
          const short4_t v = *(const short4_t*)&T[srow * 136 + c4 * 4];
          const int col = col0 + c4 * 4;
          const int hh = col >> 6, dd = col & 63;
          const int s = sbase + pass * 64 + srow;
          *(short4_t*)&((u16*)Y)[(((size_t)(bb * 16 + hh)) * 2048 + s) * 64 + dd] = v;
        }
      } else {
#pragma unroll
        for (int i = 0; i < 4; i++) {
          const int idx = tid + i * 256;           // 1024 chunks of 8 u16
          const int cl = idx >> 3, sc = idx & 7;
          const short8 v = *(const short8*)&T[cl * 72 + sc * 8];
          const int col = col0 + cl;
          const int hh = col >> 6, dd = col & 63;
          const int s = sbase + pass * 64 + sc * 8;
          *(short8*)&((u16*)Y)[(((size_t)(bb * 16 + hh)) * 64 + dd) * 2048 + s] = v;
        }
      }
    }
  }
}

__global__ __launch_bounds__(256) void qkv_kernel(
    const u16* Xq, const u16* Xk, const u16* Xv, const u16* Wq, const u16* Wk,
    const u16* Wv, const float* bq, const float* bk, const float* bv, u16* Yq,
    u16* Yk, u16* Yv) {
  __shared__ __align__(16) u16 SM[16384];
  const int z = blockIdx.z;
  const u16* X = z == 0 ? Xq : (z == 1 ? Xk : Xv);
  const u16* W = z == 0 ? Wq : (z == 1 ? Wk : Wv);
  const float* bi = z == 0 ? bq : (z == 1 ? bk : bv);
  u16* Y = z == 0 ? Yq : (z == 1 ? Yk : Yv);
  if (z == 2)
    gemm_body<2, u16, 128, 128>(SM, X, W, bi, Y, blockIdx.x * 128, blockIdx.y * 128, 1.0f);
  else
    gemm_body<1, u16, 128, 128>(SM, X, W, bi, Y, blockIdx.x * 128, blockIdx.y * 128,
                                z == 0 ? LOG2E : 1.0f);  // fold softmax 1/ln2 into Q
}

// oproj: 64x64 tiles -> 1024 blocks (4/CU) instead of 256 (1/CU).
__global__ __launch_bounds__(256) void oproj_kernel(const u16* Xc, const u16* Wo,
                                                    const float* bo, float* out) {
  __shared__ __align__(16) u16 SM[8192];
  gemm_body<0, float, 64, 64>(SM, Xc, Wo, bo, out, blockIdx.x * 64, blockIdx.y * 64, 1.0f);
}

// ---------------------------------------------------------------------------
// Flash attention (S^T trick, rel-pos). r16 = r12 attn verbatim (74.4 µs,
// best verified) + in-register relk f32->bf16 conversion in the qrel GEMM
// (rows >=33 zeroed by predicate), which removes the relk cvt slice/buffer.
// ---------------------------------------------------------------------------
__global__ __launch_bounds__(256, 6) void attn_kernel(
    const u16* __restrict__ Qg, const u16* __restrict__ Kg,
    const u16* __restrict__ Vtg, const float* __restrict__ relk,
    const float* __restrict__ relv, u16* __restrict__ ctx) {
  __shared__ __align__(16) u16 KV[8192];       // K [0,4096), V^T [4096,8192)
  __shared__ __align__(16) u16 qrelJ[64 * 33]; // Q[q]·relk[j] bf16
  __shared__ __align__(16) u16 wsum[64 * 32];  // in-band p, write-once, col31=0

  const int tid = threadIdx.x, lane = tid & 63, wid = tid >> 6;
  const int l15 = lane & 15, l16 = lane >> 4;
  const int bh = blockIdx.x;  // x-fast => all q-tiles of a bh land on one XCD
  const int b = bh >> 4, h = bh & 15;
  const int by = blockIdx.y;
  const int q0 = by * 64;
  const u16* Qb = Qg + (size_t)bh * 2048 * 64;
  const u16* Kb = Kg + (size_t)bh * 2048 * 64;
  const u16* Vtb = Vtg + (size_t)bh * 64 * 2048;  // [d][s]

  const int lrow = lane >> 3;
  const int lchunk = (lane & 7) ^ lrow;
  const int qw = wid * 16;
  const int kq4 = l16 * 4;
  const int qrow = qw + l15;

  // ---- prologue: stage Q into KV, zero wsum ----
#pragma unroll
  for (int i = 0; i < 2; i++) {
    const int rb = qw + i * 8;
    GLOAD_LDS16(Qb + (size_t)(q0 + rb + lrow) * 64 + lchunk * 8, &KV[rb * 64]);
  }
  for (int idx = tid; idx < 1024; idx += 256) ((unsigned int*)wsum)[idx] = 0u;
  __syncthreads();

  // ---- hoist Q fragment ----
  short8 aq[2];
  {
    const int m = qw + l15;
    aq[0] = *(const short8*)&KV[m * 64 + ((l16 ^ (m & 7)) * 8)];
    aq[1] = *(const short8*)&KV[m * 64 + (((4 + l16) ^ (m & 7)) * 8)];
  }
  // ---- qrel GEMM: qrelJ[q][j] = Q[q]·relk[j]; relk f32 cvt in-reg ----
  {
    f32x4 qa[3];
#pragma unroll
    for (int nt = 0; nt < 3; nt++) {
      qa[nt] = (f32x4){0.f, 0.f, 0.f, 0.f};
#pragma unroll
      for (int kk = 0; kk < 2; kk++) {
        const int rr = nt * 16 + l15;  // relk row; valid rows 0..32
        short8 bf;
        if (rr < 33) {
          const float* p = relk + rr * 64 + kk * 32 + l16 * 8;
          const float4 a = *(const float4*)p;
          const float4 b2 = *(const float4*)(p + 4);
          unsigned int o[4];
          o[0] = f2us2(a.x, a.y); o[1] = f2us2(a.z, a.w);
          o[2] = f2us2(b2.x, b2.y); o[3] = f2us2(b2.z, b2.w);
          bf = *(short8*)o;
        } else {
          bf = (short8){0, 0, 0, 0, 0, 0, 0, 0};
        }
        qa[nt] = MFMA16(aq[kk], bf, qa[nt]);
      }
    }
#pragma unroll
    for (int nt = 0; nt < 3; nt++) {
      if (nt < 2 || l15 == 0) {
#pragma unroll
        for (int r = 0; r < 4; r++)
          qrelJ[(qw + kq4 + r) * 33 + nt * 16 + l15] = f2us(qa[nt][r]);
      }
    }
  }
  WAIT_LGKM0();  // aq reads + qrelJ writes drained before KV overwrite / reads
  const float q0r = us2f(qrelJ[qrow * 33 + 0]);
  const float q32r = us2f(qrelJ[qrow * 33 + 32]);
  const f32x4 ebl = (f32x4){q0r, q0r, q0r, q0r};
  const f32x4 ebr = (f32x4){q32r, q32r, q32r, q32r};
  const f32x4 zf = (f32x4){0.f, 0.f, 0.f, 0.f};
  const short4_t ones4 = (short4_t){(short)0x3F80, (short)0x3F80,
                                    (short)0x3F80, (short)0x3F80};

  float wl_p = 0.f, wr_p = 0.f;            // diag-tile partials (VALU)
  f32x4 SL = zf, SR = zf, SD = zf;         // ones-MFMA denominator sums
  f32x4 Oacc[4];
#pragma unroll
  for (int t = 0; t < 4; t++) Oacc[t] = zf;

  // stage K/V tile k0c into LDS (single buffer, two barriers)
  auto stage = [&](int k0c) {
    SBAR();  // all waves done reading previous tile
#pragma unroll
    for (int i = 0; i < 2; i++) {
      const int rb = qw + i * 8;
      GLOAD_LDS16(Kb + (size_t)(k0c + rb + lrow) * 64 + lchunk * 8, &KV[rb * 64]);
    }
#pragma unroll
    for (int i = 0; i < 2; i++) {
      const int rb = qw + i * 8;
      GLOAD_LDS16(Vtb + (size_t)(rb + lrow) * 2048 + k0c + lchunk * 8,
                  &KV[4096 + rb * 64]);
    }
    WAIT_VM0();
    SBAR();  // tile visible to all waves
  };

  // S^T quadrant tn = K·Q^T with C-init (bias pre-folded for off-diag)
  auto qk = [&](int tn, f32x4 cin) -> f32x4 {
    const int n = tn * 16 + l15;
    const short8 bk0 = *(const short8*)&KV[n * 64 + ((l16 ^ (n & 7)) * 8)];
    const short8 bk1 = *(const short8*)&KV[n * 64 + (((4 + l16) ^ (n & 7)) * 8)];
    f32x4 s = MFMA16(bk0, aq[0], cin);
    s = MFMA16(bk1, aq[1], s);
    return s;
  };

  // O^T += V^T · P^T
  auto pvstep = [&](const short4_t* pf) {
    __builtin_amdgcn_s_setprio(1);
#pragma unroll
    for (int td = 0; td < 4; td++) {
      const int row = td * 16 + l15;
      const int rs = row & 7;
#pragma unroll
      for (int kk = 0; kk < 4; kk++) {
        const short4_t vf = *(const short4_t*)&KV[4096 + row * 64 +
                                                  (((kk * 2 + (l16 >> 1)) ^ rs) * 8) +
                                                  (l16 & 1) * 4];
        Oacc[td] = MFMAK16(vf, pf[kk], Oacc[td]);
      }
    }
    __builtin_amdgcn_s_setprio(0);
  };

  // denominator: S += colsum(P) via ones-row MFMA (matrix pipe, no VALU)
  auto psum = [&](const short4_t* pf, f32x4& S) {
#pragma unroll
    for (int kk = 0; kk < 4; kk++) S = MFMAK16(ones4, pf[kk], S);
  };

  // off-diagonal tile body: bias folded into C, no per-score bookkeeping
  auto offdiag = [&](f32x4 ebv, f32x4& S) {
    short4_t pf[4];
#pragma unroll
    for (int tn = 0; tn < 4; tn++) {
      const f32x4 sac = qk(tn, ebv);
      union { unsigned int u[2]; short4_t s; } c;
      c.u[0] = f2us2(exp2fast(sac[0]), exp2fast(sac[1]));
      c.u[1] = f2us2(exp2fast(sac[2]), exp2fast(sac[3]));
      pf[tn] = c.s;
    }
    pvstep(pf);
    psum(pf, S);
  };

  // diagonal tile body: per-element clamp/bias, in-band p to wsum
  auto diag = [&](int k0) {
    short4_t pf[4];
#pragma unroll
    for (int tn = 0; tn < 4; tn++) {
      const f32x4 sac = qk(tn, zf);
      float pv4[4];
#pragma unroll
      for (int r = 0; r < 4; r++) {
        const int kg = k0 + tn * 16 + kq4 + r;
        const int dlt = kg - (q0 + qrow);
        const int jj = (dlt < -16 ? -16 : (dlt > 16 ? 16 : dlt)) + 16;
        const float p = exp2fast(sac[r] + us2f(qrelJ[qrow * 33 + jj]));
        pv4[r] = p;
        if (dlt <= -16) wl_p += p;
        else if (dlt >= 16) wr_p += p;
        else wsum[qrow * 32 + (dlt + 15)] = f2us(p);
      }
      union { unsigned int u[2]; short4_t s; } c;
      c.u[0] = f2us2(pv4[0], pv4[1]);
      c.u[1] = f2us2(pv4[2], pv4[3]);
      pf[tn] = c.s;
    }
    pvstep(pf);
    psum(pf, SD);
  };

  // ---- main loop, split into left / diag / right tile ranges ----
  const int dlo = (by >= 1) ? by - 1 : 0;        // first diag tile
  const int dhi = (by + 2 <= 32) ? by + 2 : 32;  // one past last diag tile
  for (int kt = 0; kt < dlo; ++kt) { stage(kt * 64); offdiag(ebl, SL); }
  for (int kt = dlo; kt < dhi; ++kt) { stage(kt * 64); diag(kt * 64); }
  for (int kt = dhi; kt < 32; ++kt) { stage(kt * 64); offdiag(ebr, SR); }

  // ---- epilogue ----
  wl_p += __shfl_xor(wl_p, 16); wl_p += __shfl_xor(wl_p, 32);
  wr_p += __shfl_xor(wr_p, 16); wr_p += __shfl_xor(wr_p, 32);
  const float l_total = SL[0] + SR[0] + SD[0];   // full col sums, no shuffle
  const float linv = 1.f / l_total;
  const float wl = (SL[0] + wl_p) * linv;
  const float wr = (SR[0] + wr_p) * linv;

  // rel_v in-band term as a matmul: O^T[d][q] += sum_c relv[c+1][d]*wsum[q][c]
  {
    short4_t relf[4][2];  // A: rows d=td*16+l15, k = kk*16 + l16*4 + e
#pragma unroll
    for (int td = 0; td < 4; td++)
#pragma unroll
      for (int kk = 0; kk < 2; kk++) {
        const int jb = kk * 16 + l16 * 4 + 1;  // relv rows 1..32, all valid
        const int d = td * 16 + l15;
        union { unsigned int u[2]; short4_t s; } c;
        c.u[0] = f2us2(relv[(jb + 0) * 64 + d], relv[(jb + 1) * 64 + d]);
        c.u[1] = f2us2(relv[(jb + 2) * 64 + d], relv[(jb + 3) * 64 + d]);
        relf[td][kk] = c.s;
      }
    WAIT_LGKM0();  // wave's own wsum ds_writes drained before re-read
    short4_t wfrag[2];    // B: col q=qw+l15, k = kk*16 + l16*4 + e (col31=0)
#pragma unroll
    for (int kk = 0; kk < 2; kk++)
      wfrag[kk] = *(const short4_t*)&wsum[qrow * 32 + kk * 16 + l16 * 4];
#pragma unroll
    for (int td = 0; td < 4; td++)
#pragma unroll
      for (int kk = 0; kk < 2; kk++)
        Oacc[td] = MFMAK16(relf[td][kk], wfrag[kk], Oacc[td]);
  }

#pragma unroll
  for (int td = 0; td < 4; td++) {
    const f32x4 rv0 = *(const f32x4*)&relv[td * 16 + kq4];
    const f32x4 rv32 = *(const f32x4*)&relv[32 * 64 + td * 16 + kq4];
#pragma unroll
    for (int r = 0; r < 4; r++)
      Oacc[td][r] = Oacc[td][r] * linv + wl * rv0[r] + wr * rv32[r];
  }

  SBAR();  // all waves past their last KV reads -> KV free for O tile
  // O tile [q 64][d 64] stride 72 u16 (b128-aligned), wave-private q rows
#pragma unroll
  for (int td = 0; td < 4; td++) {
    unsigned int o[2];
    o[0] = f2us2(Oacc[td][0], Oacc[td][1]);
    o[1] = f2us2(Oacc[td][2], Oacc[td][3]);
    *(short4_t*)&KV[qrow * 72 + td * 16 + kq4] = *(short4_t*)o;
  }
  WAIT_LGKM0();
  SBAR();
#pragma unroll
  for (int i = 0; i < 2; i++) {
    const int idx = tid + i * 256;  // 512 chunks of 8 u16
    const int q = idx >> 3, sc = idx & 7;
    const short8 v = *(const short8*)&KV[q * 72 + sc * 8];
    *(short8*)&ctx[((size_t)b * 2048 + q0 + q) * 1024 + h * 64 + sc * 8] = v;
  }
}

// ---------------------------------------------------------------------------
extern "C" void kernel_launch(void* const* d_in, const int* in_sizes, int n_in,
                              void* d_out, int out_size, void* d_ws, size_t ws_size,
                              hipStream_t stream) {
  u16* qb = (u16*)d_ws;                 // [32][2048][64]
  u16* kb = qb + 4194304;               // [32][2048][64]
  u16* vtb = kb + 4194304;              // [32][64][2048]
  u16* ctx = vtb + 4194304;             // [2][2048][1024]
  u16* Xq = ctx + 4194304;
  u16* Xk = Xq + 4194304;
  u16* Xv = Xk + 4194304;
  u16* Wqb = Xv + 4194304;
  u16* Wkb = Wqb + 1048576;
  u16* Wvb = Wkb + 1048576;
  u16* Wob = Wvb + 1048576;

  const float* bq = (const float*)d_in[4];
  const float* bk = (const float*)d_in[6];
  const float* bv = (const float*)d_in[8];
  const float* bo = (const float*)d_in[10];
  const float* relk = (const float*)d_in[11];
  const float* relv = (const float*)d_in[12];

  dim3 blk(256);
  cvt_all_kernel<<<dim3(2048, 1, 7), blk, 0, stream>>>(
      (const float*)d_in[0], (const float*)d_in[1], (const float*)d_in[2],
      (const float*)d_in[3], (const float*)d_in[5], (const float*)d_in[7],
      (const float*)d_in[9], Xq, Xk, Xv, Wqb, Wkb, Wvb, Wob);
  qkv_kernel<<<dim3(32, 8, 3), blk, 0, stream>>>(Xq, Xk, Xv, Wqb, Wkb, Wvb, bq,
                                                 bk, bv, qb, kb, vtb);
  attn_kernel<<<dim3(32, 32), blk, 0, stream>>>(qb, kb, vtb, relk, relv, ctx);
  oproj_kernel<<<dim3(64, 16), blk, 0, stream>>>(ctx, Wob, bo, (float*)d_out);
}

// Round 9
// 244.677 us; speedup vs baseline: 1.1414x; 1.0413x over previous
//
#include <hip/hip_runtime.h>
#include <hip/hip_bf16.h>

typedef unsigned short u16;
typedef __attribute__((ext_vector_type(8))) short short8;
typedef __attribute__((ext_vector_type(4))) short short4_t;
typedef __attribute__((ext_vector_type(4))) float f32x4;

#define MFMA16(a, b, c) __builtin_amdgcn_mfma_f32_16x16x32_bf16((a), (b), (c), 0, 0, 0)

#if __has_builtin(__builtin_amdgcn_mfma_f32_16x16x16bf16_1k)
#define MFMAK16(a, b, c) __builtin_amdgcn_mfma_f32_16x16x16bf16_1k((a), (b), (c), 0, 0, 0)
#elif __has_builtin(__builtin_amdgcn_mfma_f32_16x16x16_bf16)
#define MFMAK16(a, b, c) __builtin_amdgcn_mfma_f32_16x16x16_bf16((a), (b), (c), 0, 0, 0)
#else
__device__ __forceinline__ f32x4 mfmak16_asm(short4_t a, short4_t b, f32x4 c) {
  asm("v_mfma_f32_16x16x16_bf16 %0, %1, %2, %0" : "+v"(c) : "v"(a), "v"(b));
  return c;
}
#define MFMAK16(a, b, c) mfmak16_asm((a), (b), (c))
#endif

#define GLOAD_LDS16(gp, lp)                                          \
  __builtin_amdgcn_global_load_lds(                                  \
      (const __attribute__((address_space(1))) void*)(gp),           \
      (__attribute__((address_space(3))) void*)(lp), 16, 0, 0)
#define SBAR() asm volatile("s_barrier" ::: "memory")
#define WAIT_LGKM0() asm volatile("s_waitcnt lgkmcnt(0)" ::: "memory")
#define WAIT_VM0() asm volatile("s_waitcnt vmcnt(0)" ::: "memory")

#define LOG2E 1.44269504088896340736f

__device__ __forceinline__ float us2f(u16 u) {
  union { unsigned int i; float f; } c; c.i = ((unsigned int)u) << 16; return c.f;
}
__device__ __forceinline__ u16 f2us(float f) {
  union { float f; unsigned int i; } c; c.f = f;
  return (u16)((c.i + 0x7fffu + ((c.i >> 16) & 1u)) >> 16);
}
__device__ __forceinline__ unsigned int f2us2(float a, float b) {
  union { __hip_bfloat162 h; unsigned int u; } c;
  c.h = __float22bfloat162_rn(float2{a, b});
  return c.u;
}
__device__ __forceinline__ float exp2fast(float x) {
#if __has_builtin(__builtin_amdgcn_exp2f)
  return __builtin_amdgcn_exp2f(x);
#else
  return exp2f(x);
#endif
}

// ---------------------------------------------------------------------------
// Fused f32 -> bf16 convert for the 7 big tensors + relk table (z=7).
// Separate pass on purpose: reads f32 ONCE at streaming BW. Fusing the
// conversion into the consumers lost twice (r15 qkv: latency-bound panel
// re-fetch; r16 relk: scattered loads on the serial prologue path, +10 µs).
// ---------------------------------------------------------------------------
__global__ __launch_bounds__(256) void cvt_all_kernel(
    const float* x0, const float* x1, const float* x2, const float* w0,
    const float* w1, const float* w2, const float* w3, const float* relk,
    u16* y0, u16* y1, u16* y2, u16* z0, u16* z1, u16* z2, u16* z3,
    u16* relkb) {
  const int z = blockIdx.z;
  if (z == 7) {
    // relk [33][64] f32 -> relkb [64][64] bf16 (rows 33..63 zero)
    const int i = (blockIdx.x * 256 + threadIdx.x) * 8;
    if (i < 4096) {
      if (i < 2112) {
        const float4 a = *(const float4*)(relk + i);
        const float4 b = *(const float4*)(relk + i + 4);
        unsigned int o[4];
        o[0] = f2us2(a.x, a.y); o[1] = f2us2(a.z, a.w);
        o[2] = f2us2(b.x, b.y); o[3] = f2us2(b.z, b.w);
        *(uint4*)(relkb + i) = *(uint4*)o;
      } else {
        uint4 zz = {0u, 0u, 0u, 0u};
        *(uint4*)(relkb + i) = zz;
      }
    }
    return;
  }
  const float* src; u16* dst; int n;
  switch (z) {
    case 0: src = x0; dst = y0; n = 4194304; break;
    case 1: src = x1; dst = y1; n = 4194304; break;
    case 2: src = x2; dst = y2; n = 4194304; break;
    case 3: src = w0; dst = z0; n = 1048576; break;
    case 4: src = w1; dst = z1; n = 1048576; break;
    case 5: src = w2; dst = z2; n = 1048576; break;
    default: src = w3; dst = z3; n = 1048576; break;
  }
  const int i = (blockIdx.x * 256 + threadIdx.x) * 8;
  if (i < n) {
    const float4 a = *(const float4*)(src + i);
    const float4 b = *(const float4*)(src + i + 4);
    unsigned int o[4];
    o[0] = f2us2(a.x, a.y); o[1] = f2us2(a.z, a.w);
    o[2] = f2us2(b.x, b.y); o[3] = f2us2(b.z, b.w);
    *(uint4*)(dst + i) = *(uint4*)o;
  }
}

// ---------------------------------------------------------------------------
// GEMM: Y = (X @ W^T + bias) * oscale.  BM x BN block tile, 4 waves (2x2).
// MODE 0: f32 row-major [4096][1024].  MODE 1: u16 [bh][s][d].  MODE 2:
// u16 [bh][d][s].  Modes 1/2 (BM=BN=128 only) write through an LDS transpose.
// ---------------------------------------------------------------------------
template <int MODE, typename OUT, int BM, int BN>
__device__ __forceinline__ void gemm_body(u16* __restrict__ SM,
                                          const u16* __restrict__ X,
                                          const u16* __restrict__ W,
                                          const float* __restrict__ bias,
                                          OUT* __restrict__ Y, int row0, int col0,
                                          float oscale) {
  constexpr int TM = BM / 32, TN = BN / 32;  // 16-row tiles per wave
  u16* As = SM;              // [BM][64]
  u16* Bs = SM + BM * 64;    // [BN][64]
  const int tid = threadIdx.x;
  const int lane = tid & 63;
  const int wid = tid >> 6;
  const int wm = wid >> 1, wn = wid & 1;
  const int l15 = lane & 15, l16 = lane >> 4;
  const int lrow = lane >> 3;
  const int lchunk = (lane & 7) ^ lrow;

  f32x4 acc[TM][TN];
#pragma unroll
  for (int i = 0; i < TM; i++)
#pragma unroll
    for (int j = 0; j < TN; j++) acc[i][j] = (f32x4){0.f, 0.f, 0.f, 0.f};

  for (int k0 = 0; k0 < 1024; k0 += 64) {
#pragma unroll
    for (int i = 0; i < TM; i++) {
      const int rb = (wid * TM + i) * 8;
      GLOAD_LDS16(X + (size_t)(row0 + rb + lrow) * 1024 + k0 + lchunk * 8, &As[rb * 64]);
    }
#pragma unroll
    for (int i = 0; i < TN; i++) {
      const int rb = (wid * TN + i) * 8;
      GLOAD_LDS16(W + (size_t)(col0 + rb + lrow) * 1024 + k0 + lchunk * 8, &Bs[rb * 64]);
    }
    __syncthreads();
#pragma unroll
    for (int kk = 0; kk < 2; kk++) {
      const int ch = kk * 4 + l16;
      short8 af[TM], bfr[TN];
#pragma unroll
      for (int t = 0; t < TM; t++) {
        const int m = wm * (BM / 2) + t * 16 + l15;
        af[t] = *(const short8*)&As[m * 64 + ((ch ^ (m & 7)) * 8)];
      }
#pragma unroll
      for (int t = 0; t < TN; t++) {
        const int n = wn * (BN / 2) + t * 16 + l15;
        bfr[t] = *(const short8*)&Bs[n * 64 + ((ch ^ (n & 7)) * 8)];
      }
#pragma unroll
      for (int tm = 0; tm < TM; tm++)
#pragma unroll
        for (int tn = 0; tn < TN; tn++)
          acc[tm][tn] = MFMA16(af[tm], bfr[tn], acc[tm][tn]);
    }
    __syncthreads();
  }

  if (MODE == 0) {
#pragma unroll
    for (int tn = 0; tn < TN; tn++) {
      const int col = col0 + wn * (BN / 2) + tn * 16 + l15;
      const float bv = bias[col];
#pragma unroll
      for (int tm = 0; tm < TM; tm++) {
        const int rowb = row0 + wm * (BM / 2) + tm * 16 + l16 * 4;
#pragma unroll
        for (int r = 0; r < 4; r++)
          Y[(size_t)(rowb + r) * 1024 + col] = (OUT)(acc[tm][tn][r] + bv);
      }
    }
  } else {
    // LDS-transpose epilogue (BM=BN=128 only), two 64-row passes.
    u16* T = SM;
    const int bb = row0 >> 11;
    const int sbase = row0 & 2047;
#pragma unroll
    for (int pass = 0; pass < 2; pass++) {
      __syncthreads();
      if (wm == pass) {
#pragma unroll
        for (int tn = 0; tn < TN; tn++) {
          const int coll = wn * 64 + tn * 16 + l15;
          const float bv = bias[col0 + coll];
#pragma unroll
          for (int tm = 0; tm < TM; tm++) {
            if (MODE == 1) {
#pragma unroll
              for (int r = 0; r < 4; r++)
                T[(tm * 16 + l16 * 4 + r) * 136 + coll] = f2us((acc[tm][tn][r] + bv) * oscale);
            } else {
              unsigned int o[2];
              o[0] = f2us2(acc[tm][tn][0] + bv, acc[tm][tn][1] + bv);
              o[1] = f2us2(acc[tm][tn][2] + bv, acc[tm][tn][3] + bv);
              *(short4_t*)&T[coll * 72 + tm * 16 + l16 * 4] = *(short4_t*)o;
            }
          }
        }
      }
      __syncthreads();
      if (MODE == 1) {
#pragma unroll
        for (int i = 0; i < 8; i++) {
          const int idx = tid + i * 256;           // 2048 chunks of 4 u16
          const int srow = idx >> 5, c4 = idx & 31;
          const short4_t v = *(const short4_t*)&T[srow * 136 + c4 * 4];
          const int col = col0 + c4 * 4;
          const int hh = col >> 6, dd = col & 63;
          const int s = sbase + pass * 64 + srow;
          *(short4_t*)&((u16*)Y)[(((size_t)(bb * 16 + hh)) * 2048 + s) * 64 + dd] = v;
        }
      } else {
#pragma unroll
        for (int i = 0; i < 4; i++) {
          const int idx = tid + i * 256;           // 1024 chunks of 8 u16
          const int cl = idx >> 3, sc = idx & 7;
          const short8 v = *(const short8*)&T[cl * 72 + sc * 8];
          const int col = col0 + cl;
          const int hh = col >> 6, dd = col & 63;
          const int s = sbase + pass * 64 + sc * 8;
          *(short8*)&((u16*)Y)[(((size_t)(bb * 16 + hh)) * 64 + dd) * 2048 + s] = v;
        }
      }
    }
  }
}

__global__ __launch_bounds__(256) void qkv_kernel(
    const u16* Xq, const u16* Xk, const u16* Xv, const u16* Wq, const u16* Wk,
    const u16* Wv, const float* bq, const float* bk, const float* bv, u16* Yq,
    u16* Yk, u16* Yv) {
  __shared__ __align__(16) u16 SM[16384];
  const int z = blockIdx.z;
  const u16* X = z == 0 ? Xq : (z == 1 ? Xk : Xv);
  const u16* W = z == 0 ? Wq : (z == 1 ? Wk : Wv);
  const float* bi = z == 0 ? bq : (z == 1 ? bk : bv);
  u16* Y = z == 0 ? Yq : (z == 1 ? Yk : Yv);
  if (z == 2)
    gemm_body<2, u16, 128, 128>(SM, X, W, bi, Y, blockIdx.x * 128, blockIdx.y * 128, 1.0f);
  else
    gemm_body<1, u16, 128, 128>(SM, X, W, bi, Y, blockIdx.x * 128, blockIdx.y * 128,
                                z == 0 ? LOG2E : 1.0f);  // fold softmax 1/ln2 into Q
}

// oproj: 64x64 tiles -> 1024 blocks (4/CU) instead of 256 (1/CU).
__global__ __launch_bounds__(256) void oproj_kernel(const u16* Xc, const u16* Wo,
                                                    const float* bo, float* out) {
  __shared__ __align__(16) u16 SM[8192];
  gemm_body<0, float, 64, 64>(SM, Xc, Wo, bo, out, blockIdx.x * 64, blockIdx.y * 64, 1.0f);
}

// ---------------------------------------------------------------------------
// Flash attention (S^T trick, rel-pos). r17 = r12 attn verbatim (74.4 µs,
// best verified): K+V staged via global_load_lds (single buffer), XOR-swizzled
// K, V b64 reads (2-way conflicts ~free per m136), MFMA denominator (ones-row),
// MFMA rel_v epilogue, bias folded into QK C-operand, exp2 with Q prescale.
// relkb is the precomputed bf16 table (cvt_all z=7).
// ---------------------------------------------------------------------------
__global__ __launch_bounds__(256, 6) void attn_kernel(
    const u16* __restrict__ Qg, const u16* __restrict__ Kg,
    const u16* __restrict__ Vtg, const u16* __restrict__ relkb,
    const float* __restrict__ relv, u16* __restrict__ ctx) {
  __shared__ __align__(16) u16 KV[8192];       // K [0,4096), V^T [4096,8192)
  __shared__ __align__(16) u16 qrelJ[64 * 33]; // Q[q]·relk[j] bf16
  __shared__ __align__(16) u16 wsum[64 * 32];  // in-band p, write-once, col31=0

  const int tid = threadIdx.x, lane = tid & 63, wid = tid >> 6;
  const int l15 = lane & 15, l16 = lane >> 4;
  const int bh = blockIdx.x;  // x-fast => all q-tiles of a bh land on one XCD
  const int b = bh >> 4, h = bh & 15;
  const int by = blockIdx.y;
  const int q0 = by * 64;
  const u16* Qb = Qg + (size_t)bh * 2048 * 64;
  const u16* Kb = Kg + (size_t)bh * 2048 * 64;
  const u16* Vtb = Vtg + (size_t)bh * 64 * 2048;  // [d][s]

  const int lrow = lane >> 3;
  const int lchunk = (lane & 7) ^ lrow;
  const int qw = wid * 16;
  const int kq4 = l16 * 4;
  const int qrow = qw + l15;

  // ---- prologue: stage Q into KV, zero wsum ----
#pragma unroll
  for (int i = 0; i < 2; i++) {
    const int rb = qw + i * 8;
    GLOAD_LDS16(Qb + (size_t)(q0 + rb + lrow) * 64 + lchunk * 8, &KV[rb * 64]);
  }
  for (int idx = tid; idx < 1024; idx += 256) ((unsigned int*)wsum)[idx] = 0u;
  __syncthreads();

  // ---- hoist Q fragment ----
  short8 aq[2];
  {
    const int m = qw + l15;
    aq[0] = *(const short8*)&KV[m * 64 + ((l16 ^ (m & 7)) * 8)];
    aq[1] = *(const short8*)&KV[m * 64 + (((4 + l16) ^ (m & 7)) * 8)];
  }
  // ---- qrel GEMM: qrelJ[q][j] = Q[q]·relk[j] ----
  {
    f32x4 qa[3];
#pragma unroll
    for (int nt = 0; nt < 3; nt++) {
      qa[nt] = (f32x4){0.f, 0.f, 0.f, 0.f};
#pragma unroll
      for (int kk = 0; kk < 2; kk++) {
        const short8 bf =
            *(const short8*)(relkb + (nt * 16 + l15) * 64 + kk * 32 + l16 * 8);
        qa[nt] = MFMA16(aq[kk], bf, qa[nt]);
      }
    }
#pragma unroll
    for (int nt = 0; nt < 3; nt++) {
      if (nt < 2 || l15 == 0) {
#pragma unroll
        for (int r = 0; r < 4; r++)
          qrelJ[(qw + kq4 + r) * 33 + nt * 16 + l15] = f2us(qa[nt][r]);
      }
    }
  }
  WAIT_LGKM0();  // aq reads + qrelJ writes drained before KV overwrite / reads
  const float q0r = us2f(qrelJ[qrow * 33 + 0]);
  const float q32r = us2f(qrelJ[qrow * 33 + 32]);
  const f32x4 ebl = (f32x4){q0r, q0r, q0r, q0r};
  const f32x4 ebr = (f32x4){q32r, q32r, q32r, q32r};
  const f32x4 zf = (f32x4){0.f, 0.f, 0.f, 0.f};
  const short4_t ones4 = (short4_t){(short)0x3F80, (short)0x3F80,
                                    (short)0x3F80, (short)0x3F80};

  float wl_p = 0.f, wr_p = 0.f;            // diag-tile partials (VALU)
  f32x4 SL = zf, SR = zf, SD = zf;         // ones-MFMA denominator sums
  f32x4 Oacc[4];
#pragma unroll
  for (int t = 0; t < 4; t++) Oacc[t] = zf;

  // stage K/V tile k0c into LDS (single buffer, two barriers)
  auto stage = [&](int k0c) {
    SBAR();  // all waves done reading previous tile
#pragma unroll
    for (int i = 0; i < 2; i++) {
      const int rb = qw + i * 8;
      GLOAD_LDS16(Kb + (size_t)(k0c + rb + lrow) * 64 + lchunk * 8, &KV[rb * 64]);
    }
#pragma unroll
    for (int i = 0; i < 2; i++) {
      const int rb = qw + i * 8;
      GLOAD_LDS16(Vtb + (size_t)(rb + lrow) * 2048 + k0c + lchunk * 8,
                  &KV[4096 + rb * 64]);
    }
    WAIT_VM0();
    SBAR();  // tile visible to all waves
  };

  // S^T quadrant tn = K·Q^T with C-init (bias pre-folded for off-diag)
  auto qk = [&](int tn, f32x4 cin) -> f32x4 {
    const int n = tn * 16 + l15;
    const short8 bk0 = *(const short8*)&KV[n * 64 + ((l16 ^ (n & 7)) * 8)];
    const short8 bk1 = *(const short8*)&KV[n * 64 + (((4 + l16) ^ (n & 7)) * 8)];
    f32x4 s = MFMA16(bk0, aq[0], cin);
    s = MFMA16(bk1, aq[1], s);
    return s;
  };

  // O^T += V^T · P^T
  auto pvstep = [&](const short4_t* pf) {
    __builtin_amdgcn_s_setprio(1);
#pragma unroll
    for (int td = 0; td < 4; td++) {
      const int row = td * 16 + l15;
      const int rs = row & 7;
#pragma unroll
      for (int kk = 0; kk < 4; kk++) {
        const short4_t vf = *(const short4_t*)&KV[4096 + row * 64 +
                                                  (((kk * 2 + (l16 >> 1)) ^ rs) * 8) +
                                                  (l16 & 1) * 4];
        Oacc[td] = MFMAK16(vf, pf[kk], Oacc[td]);
      }
    }
    __builtin_amdgcn_s_setprio(0);
  };

  // denominator: S += colsum(P) via ones-row MFMA (matrix pipe, no VALU)
  auto psum = [&](const short4_t* pf, f32x4& S) {
#pragma unroll
    for (int kk = 0; kk < 4; kk++) S = MFMAK16(ones4, pf[kk], S);
  };

  // off-diagonal tile body: bias folded into C, no per-score bookkeeping
  auto offdiag = [&](f32x4 ebv, f32x4& S) {
    short4_t pf[4];
#pragma unroll
    for (int tn = 0; tn < 4; tn++) {
      const f32x4 sac = qk(tn, ebv);
      union { unsigned int u[2]; short4_t s; } c;
      c.u[0] = f2us2(exp2fast(sac[0]), exp2fast(sac[1]));
      c.u[1] = f2us2(exp2fast(sac[2]), exp2fast(sac[3]));
      pf[tn] = c.s;
    }
    pvstep(pf);
    psum(pf, S);
  };

  // diagonal tile body: per-element clamp/bias, in-band p to wsum
  auto diag = [&](int k0) {
    short4_t pf[4];
#pragma unroll
    for (int tn = 0; tn < 4; tn++) {
      const f32x4 sac = qk(tn, zf);
      float pv4[4];
#pragma unroll
      for (int r = 0; r < 4; r++) {
        const int kg = k0 + tn * 16 + kq4 + r;
        const int dlt = kg - (q0 + qrow);
        const int jj = (dlt < -16 ? -16 : (dlt > 16 ? 16 : dlt)) + 16;
        const float p = exp2fast(sac[r] + us2f(qrelJ[qrow * 33 + jj]));
        pv4[r] = p;
        if (dlt <= -16) wl_p += p;
        else if (dlt >= 16) wr_p += p;
        else wsum[qrow * 32 + (dlt + 15)] = f2us(p);
      }
      union { unsigned int u[2]; short4_t s; } c;
      c.u[0] = f2us2(pv4[0], pv4[1]);
      c.u[1] = f2us2(pv4[2], pv4[3]);
      pf[tn] = c.s;
    }
    pvstep(pf);
    psum(pf, SD);
  };

  // ---- main loop, split into left / diag / right tile ranges ----
  const int dlo = (by >= 1) ? by - 1 : 0;        // first diag tile
  const int dhi = (by + 2 <= 32) ? by + 2 : 32;  // one past last diag tile
  for (int kt = 0; kt < dlo; ++kt) { stage(kt * 64); offdiag(ebl, SL); }
  for (int kt = dlo; kt < dhi; ++kt) { stage(kt * 64); diag(kt * 64); }
  for (int kt = dhi; kt < 32; ++kt) { stage(kt * 64); offdiag(ebr, SR); }

  // ---- epilogue ----
  wl_p += __shfl_xor(wl_p, 16); wl_p += __shfl_xor(wl_p, 32);
  wr_p += __shfl_xor(wr_p, 16); wr_p += __shfl_xor(wr_p, 32);
  const float l_total = SL[0] + SR[0] + SD[0];   // full col sums, no shuffle
  const float linv = 1.f / l_total;
  const float wl = (SL[0] + wl_p) * linv;
  const float wr = (SR[0] + wr_p) * linv;

  // rel_v in-band term as a matmul: O^T[d][q] += sum_c relv[c+1][d]*wsum[q][c]
  {
    short4_t relf[4][2];  // A: rows d=td*16+l15, k = kk*16 + l16*4 + e
#pragma unroll
    for (int td = 0; td < 4; td++)
#pragma unroll
      for (int kk = 0; kk < 2; kk++) {
        const int jb = kk * 16 + l16 * 4 + 1;  // relv rows 1..32, all valid
        const int d = td * 16 + l15;
        union { unsigned int u[2]; short4_t s; } c;
        c.u[0] = f2us2(relv[(jb + 0) * 64 + d], relv[(jb + 1) * 64 + d]);
        c.u[1] = f2us2(relv[(jb + 2) * 64 + d], relv[(jb + 3) * 64 + d]);
        relf[td][kk] = c.s;
      }
    WAIT_LGKM0();  // wave's own wsum ds_writes drained before re-read
    short4_t wfrag[2];    // B: col q=qw+l15, k = kk*16 + l16*4 + e (col31=0)
#pragma unroll
    for (int kk = 0; kk < 2; kk++)
      wfrag[kk] = *(const short4_t*)&wsum[qrow * 32 + kk * 16 + l16 * 4];
#pragma unroll
    for (int td = 0; td < 4; td++)
#pragma unroll
      for (int kk = 0; kk < 2; kk++)
        Oacc[td] = MFMAK16(relf[td][kk], wfrag[kk], Oacc[td]);
  }

#pragma unroll
  for (int td = 0; td < 4; td++) {
    const f32x4 rv0 = *(const f32x4*)&relv[td * 16 + kq4];
    const f32x4 rv32 = *(const f32x4*)&relv[32 * 64 + td * 16 + kq4];
#pragma unroll
    for (int r = 0; r < 4; r++)
      Oacc[td][r] = Oacc[td][r] * linv + wl * rv0[r] + wr * rv32[r];
  }

  SBAR();  // all waves past their last KV reads -> KV free for O tile
  // O tile [q 64][d 64] stride 72 u16 (b128-aligned), wave-private q rows
#pragma unroll
  for (int td = 0; td < 4; td++) {
    unsigned int o[2];
    o[0] = f2us2(Oacc[td][0], Oacc[td][1]);
    o[1] = f2us2(Oacc[td][2], Oacc[td][3]);
    *(short4_t*)&KV[qrow * 72 + td * 16 + kq4] = *(short4_t*)o;
  }
  WAIT_LGKM0();
  SBAR();
#pragma unroll
  for (int i = 0; i < 2; i++) {
    const int idx = tid + i * 256;  // 512 chunks of 8 u16
    const int q = idx >> 3, sc = idx & 7;
    const short8 v = *(const short8*)&KV[q * 72 + sc * 8];
    *(short8*)&ctx[((size_t)b * 2048 + q0 + q) * 1024 + h * 64 + sc * 8] = v;
  }
}

// ---------------------------------------------------------------------------
extern "C" void kernel_launch(void* const* d_in, const int* in_sizes, int n_in,
                              void* d_out, int out_size, void* d_ws, size_t ws_size,
                              hipStream_t stream) {
  u16* qb = (u16*)d_ws;                 // [32][2048][64]
  u16* kb = qb + 4194304;               // [32][2048][64]
  u16* vtb = kb + 4194304;              // [32][64][2048]
  u16* ctx = vtb + 4194304;             // [2][2048][1024]
  u16* Xq = ctx + 4194304;
  u16* Xk = Xq + 4194304;
  u16* Xv = Xk + 4194304;
  u16* Wqb = Xv + 4194304;
  u16* Wkb = Wqb + 1048576;
  u16* Wvb = Wkb + 1048576;
  u16* Wob = Wvb + 1048576;
  u16* relkb = Wob + 1048576;           // [64][64] bf16

  const float* bq = (const float*)d_in[4];
  const float* bk = (const float*)d_in[6];
  const float* bv = (const float*)d_in[8];
  const float* bo = (const float*)d_in[10];
  const float* relk = (const float*)d_in[11];
  const float* relv = (const float*)d_in[12];

  dim3 blk(256);
  cvt_all_kernel<<<dim3(2048, 1, 8), blk, 0, stream>>>(
      (const float*)d_in[0], (const float*)d_in[1], (const float*)d_in[2],
      (const float*)d_in[3], (const float*)d_in[5], (const float*)d_in[7],
      (const float*)d_in[9], relk, Xq, Xk, Xv, Wqb, Wkb, Wvb, Wob, relkb);
  qkv_kernel<<<dim3(32, 8, 3), blk, 0, stream>>>(Xq, Xk, Xv, Wqb, Wkb, Wvb, bq,
                                                 bk, bv, qb, kb, vtb);
  attn_kernel<<<dim3(32, 32), blk, 0, stream>>>(qb, kb, vtb, relkb, relv, ctx);
  oproj_kernel<<<dim3(64, 16), blk, 0, stream>>>(ctx, Wob, bo, (float*)d_out);
}

// Round 10
// 243.440 us; speedup vs baseline: 1.1472x; 1.0051x over previous
//
#include <hip/hip_runtime.h>
#include <hip/hip_bf16.h>

typedef unsigned short u16;
typedef __attribute__((ext_vector_type(8))) short short8;
typedef __attribute__((ext_vector_type(4))) short short4_t;
typedef __attribute__((ext_vector_type(4))) float f32x4;

#define MFMA16(a, b, c) __builtin_amdgcn_mfma_f32_16x16x32_bf16((a), (b), (c), 0, 0, 0)

#if __has_builtin(__builtin_amdgcn_mfma_f32_16x16x16bf16_1k)
#define MFMAK16(a, b, c) __builtin_amdgcn_mfma_f32_16x16x16bf16_1k((a), (b), (c), 0, 0, 0)
#elif __has_builtin(__builtin_amdgcn_mfma_f32_16x16x16_bf16)
#define MFMAK16(a, b, c) __builtin_amdgcn_mfma_f32_16x16x16_bf16((a), (b), (c), 0, 0, 0)
#else
__device__ __forceinline__ f32x4 mfmak16_asm(short4_t a, short4_t b, f32x4 c) {
  asm("v_mfma_f32_16x16x16_bf16 %0, %1, %2, %0" : "+v"(c) : "v"(a), "v"(b));
  return c;
}
#define MFMAK16(a, b, c) mfmak16_asm((a), (b), (c))
#endif

#define GLOAD_LDS16(gp, lp)                                          \
  __builtin_amdgcn_global_load_lds(                                  \
      (const __attribute__((address_space(1))) void*)(gp),           \
      (__attribute__((address_space(3))) void*)(lp), 16, 0, 0)
#define SBAR() asm volatile("s_barrier" ::: "memory")
#define WAIT_LGKM0() asm volatile("s_waitcnt lgkmcnt(0)" ::: "memory")
#define WAIT_VM0() asm volatile("s_waitcnt vmcnt(0)" ::: "memory")

#define LOG2E 1.44269504088896340736f

__device__ __forceinline__ float us2f(u16 u) {
  union { unsigned int i; float f; } c; c.i = ((unsigned int)u) << 16; return c.f;
}
__device__ __forceinline__ u16 f2us(float f) {
  union { float f; unsigned int i; } c; c.f = f;
  return (u16)((c.i + 0x7fffu + ((c.i >> 16) & 1u)) >> 16);
}
__device__ __forceinline__ unsigned int f2us2(float a, float b) {
  union { __hip_bfloat162 h; unsigned int u; } c;
  c.h = __float22bfloat162_rn(float2{a, b});
  return c.u;
}
__device__ __forceinline__ float exp2fast(float x) {
#if __has_builtin(__builtin_amdgcn_exp2f)
  return __builtin_amdgcn_exp2f(x);
#else
  return exp2f(x);
#endif
}

// ---------------------------------------------------------------------------
// Fused f32 -> bf16 convert for the 7 big tensors + relk table (z=7).
// Separate pass on purpose: reads f32 ONCE at streaming BW. Fusing the
// conversion into the consumers lost twice (r15 qkv: latency-bound panel
// re-fetch; r16 relk: scattered loads on the serial prologue path, +10 µs).
// ---------------------------------------------------------------------------
__global__ __launch_bounds__(256) void cvt_all_kernel(
    const float* x0, const float* x1, const float* x2, const float* w0,
    const float* w1, const float* w2, const float* w3, const float* relk,
    u16* y0, u16* y1, u16* y2, u16* z0, u16* z1, u16* z2, u16* z3,
    u16* relkb) {
  const int z = blockIdx.z;
  if (z == 7) {
    // relk [33][64] f32 -> relkb [64][64] bf16 (rows 33..63 zero)
    const int i = (blockIdx.x * 256 + threadIdx.x) * 8;
    if (i < 4096) {
      if (i < 2112) {
        const float4 a = *(const float4*)(relk + i);
        const float4 b = *(const float4*)(relk + i + 4);
        unsigned int o[4];
        o[0] = f2us2(a.x, a.y); o[1] = f2us2(a.z, a.w);
        o[2] = f2us2(b.x, b.y); o[3] = f2us2(b.z, b.w);
        *(uint4*)(relkb + i) = *(uint4*)o;
      } else {
        uint4 zz = {0u, 0u, 0u, 0u};
        *(uint4*)(relkb + i) = zz;
      }
    }
    return;
  }
  const float* src; u16* dst; int n;
  switch (z) {
    case 0: src = x0; dst = y0; n = 4194304; break;
    case 1: src = x1; dst = y1; n = 4194304; break;
    case 2: src = x2; dst = y2; n = 4194304; break;
    case 3: src = w0; dst = z0; n = 1048576; break;
    case 4: src = w1; dst = z1; n = 1048576; break;
    case 5: src = w2; dst = z2; n = 1048576; break;
    default: src = w3; dst = z3; n = 1048576; break;
  }
  const int i = (blockIdx.x * 256 + threadIdx.x) * 8;
  if (i < n) {
    const float4 a = *(const float4*)(src + i);
    const float4 b = *(const float4*)(src + i + 4);
    unsigned int o[4];
    o[0] = f2us2(a.x, a.y); o[1] = f2us2(a.z, a.w);
    o[2] = f2us2(b.x, b.y); o[3] = f2us2(b.z, b.w);
    *(uint4*)(dst + i) = *(uint4*)o;
  }
}

// ---------------------------------------------------------------------------
// GEMM: Y = (X @ W^T + bias) * oscale.  BM x BN block tile, 4 waves (2x2),
// BK-deep K-steps (BK=64 or 128). Staging: BK/8 16B-chunks per row,
// 512/BK rows per gload instruction, XOR swizzle ch^(row&7) (fragment b128
// reads stay 2-way ~free). BK=64 path is byte-identical to the verified r12
// code. BK=128 halves barrier/vmcnt sync points (same gload and MFMA counts,
// same K-accumulation order -> bitwise-identical results).
// MODE 0: f32 row-major [4096][1024].  MODE 1: u16 [bh][s][d].  MODE 2:
// u16 [bh][d][s].  Modes 1/2 (BM=BN=128, BK=64 only) use an LDS transpose.
// ---------------------------------------------------------------------------
template <int MODE, typename OUT, int BM, int BN, int BK>
__device__ __forceinline__ void gemm_body(u16* __restrict__ SM,
                                          const u16* __restrict__ X,
                                          const u16* __restrict__ W,
                                          const float* __restrict__ bias,
                                          OUT* __restrict__ Y, int row0, int col0,
                                          float oscale) {
  constexpr int TM = BM / 32, TN = BN / 32;  // 16-row tiles per wave
  constexpr int CH = BK / 8;                 // 16B chunks per row
  constexpr int RPG = 64 / CH;               // rows per gload instruction
  constexpr int NGA = BM / (4 * RPG);        // A gloads per wave per k-step
  constexpr int NGB = BN / (4 * RPG);        // B gloads per wave per k-step
  u16* As = SM;              // [BM][BK]
  u16* Bs = SM + BM * BK;    // [BN][BK]
  const int tid = threadIdx.x;
  const int lane = tid & 63;
  const int wid = tid >> 6;
  const int wm = wid >> 1, wn = wid & 1;
  const int l15 = lane & 15, l16 = lane >> 4;
  const int lrow = lane / CH;   // row within gload group
  const int lch = lane % CH;    // chunk within row

  f32x4 acc[TM][TN];
#pragma unroll
  for (int i = 0; i < TM; i++)
#pragma unroll
    for (int j = 0; j < TN; j++) acc[i][j] = (f32x4){0.f, 0.f, 0.f, 0.f};

  for (int k0 = 0; k0 < 1024; k0 += BK) {
#pragma unroll
    for (int i = 0; i < NGA; i++) {
      const int rb = (wid * NGA + i) * RPG;
      const int row = rb + lrow;
      GLOAD_LDS16(X + (size_t)(row0 + row) * 1024 + k0 + ((lch ^ (row & 7)) * 8),
                  &As[rb * BK]);
    }
#pragma unroll
    for (int i = 0; i < NGB; i++) {
      const int rb = (wid * NGB + i) * RPG;
      const int row = rb + lrow;
      GLOAD_LDS16(W + (size_t)(col0 + row) * 1024 + k0 + ((lch ^ (row & 7)) * 8),
                  &Bs[rb * BK]);
    }
    __syncthreads();
#pragma unroll
    for (int kk = 0; kk < BK / 32; kk++) {
      const int ch = kk * 4 + l16;
      short8 af[TM], bfr[TN];
#pragma unroll
      for (int t = 0; t < TM; t++) {
        const int m = wm * (BM / 2) + t * 16 + l15;
        af[t] = *(const short8*)&As[m * BK + ((ch ^ (m & 7)) * 8)];
      }
#pragma unroll
      for (int t = 0; t < TN; t++) {
        const int n = wn * (BN / 2) + t * 16 + l15;
        bfr[t] = *(const short8*)&Bs[n * BK + ((ch ^ (n & 7)) * 8)];
      }
#pragma unroll
      for (int tm = 0; tm < TM; tm++)
#pragma unroll
        for (int tn = 0; tn < TN; tn++)
          acc[tm][tn] = MFMA16(af[tm], bfr[tn], acc[tm][tn]);
    }
    __syncthreads();
  }

  if (MODE == 0) {
#pragma unroll
    for (int tn = 0; tn < TN; tn++) {
      const int col = col0 + wn * (BN / 2) + tn * 16 + l15;
      const float bv = bias[col];
#pragma unroll
      for (int tm = 0; tm < TM; tm++) {
        const int rowb = row0 + wm * (BM / 2) + tm * 16 + l16 * 4;
#pragma unroll
        for (int r = 0; r < 4; r++)
          Y[(size_t)(rowb + r) * 1024 + col] = (OUT)(acc[tm][tn][r] + bv);
      }
    }
  } else {
    // LDS-transpose epilogue (BM=BN=128 only), two 64-row passes.
    u16* T = SM;
    const int bb = row0 >> 11;
    const int sbase = row0 & 2047;
#pragma unroll
    for (int pass = 0; pass < 2; pass++) {
      __syncthreads();
      if (wm == pass) {
#pragma unroll
        for (int tn = 0; tn < TN; tn++) {
          const int coll = wn * 64 + tn * 16 + l15;
          const float bv = bias[col0 + coll];
#pragma unroll
          for (int tm = 0; tm < TM; tm++) {
            if (MODE == 1) {
#pragma unroll
              for (int r = 0; r < 4; r++)
                T[(tm * 16 + l16 * 4 + r) * 136 + coll] = f2us((acc[tm][tn][r] + bv) * oscale);
            } else {
              unsigned int o[2];
              o[0] = f2us2(acc[tm][tn][0] + bv, acc[tm][tn][1] + bv);
              o[1] = f2us2(acc[tm][tn][2] + bv, acc[tm][tn][3] + bv);
              *(short4_t*)&T[coll * 72 + tm * 16 + l16 * 4] = *(short4_t*)o;
            }
          }
        }
      }
      __syncthreads();
      if (MODE == 1) {
#pragma unroll
        for (int i = 0; i < 8; i++) {
          const int idx = tid + i * 256;           // 2048 chunks of 4 u16
          const int srow = idx >> 5, c4 = idx & 31;
          const short4_t v = *(const short4_t*)&T[srow * 136 + c4 * 4];
          const int col = col0 + c4 * 4;
          const int hh = col >> 6, dd = col & 63;
          const int s = sbase + pass * 64 + srow;
          *(short4_t*)&((u16*)Y)[(((size_t)(bb * 16 + hh)) * 2048 + s) * 64 + dd] = v;
        }
      } else {
#pragma unroll
        for (int i = 0; i < 4; i++) {
          const int idx = tid + i * 256;           // 1024 chunks of 8 u16
          const int cl = idx >> 3, sc = idx & 7;
          const short8 v = *(const short8*)&T[cl * 72 + sc * 8];
          const int col = col0 + cl;
          const int hh = col >> 6, dd = col & 63;
          const int s = sbase + pass * 64 + sc * 8;
          *(short8*)&((u16*)Y)[(((size_t)(bb * 16 + hh)) * 64 + dd) * 2048 + s] = v;
        }
      }
    }
  }
}

__global__ __launch_bounds__(256) void qkv_kernel(
    const u16* Xq, const u16* Xk, const u16* Xv, const u16* Wq, const u16* Wk,
    const u16* Wv, const float* bq, const float* bk, const float* bv, u16* Yq,
    u16* Yk, u16* Yv) {
  __shared__ __align__(16) u16 SM[16384];
  const int z = blockIdx.z;
  const u16* X = z == 0 ? Xq : (z == 1 ? Xk : Xv);
  const u16* W = z == 0 ? Wq : (z == 1 ? Wk : Wv);
  const float* bi = z == 0 ? bq : (z == 1 ? bk : bv);
  u16* Y = z == 0 ? Yq : (z == 1 ? Yk : Yv);
  if (z == 2)
    gemm_body<2, u16, 128, 128, 64>(SM, X, W, bi, Y, blockIdx.x * 128,
                                    blockIdx.y * 128, 1.0f);
  else
    gemm_body<1, u16, 128, 128, 64>(SM, X, W, bi, Y, blockIdx.x * 128,
                                    blockIdx.y * 128,
                                    z == 0 ? LOG2E : 1.0f);  // fold 1/ln2 into Q
}

// oproj: 64x64 tiles (1024 blocks = 4/CU), BK=128: halves barrier/vmcnt sync
// points vs BK=64 (worst MFMA:sync ratio of the 3 GEMMs). LDS 32 KB -> 5/CU
// capacity >= 4/CU grid limit, so no occupancy loss (m132's BK=128 regression
// was the 64 KB / 2-blocks case).
__global__ __launch_bounds__(256) void oproj_kernel(const u16* Xc, const u16* Wo,
                                                    const float* bo, float* out) {
  __shared__ __align__(16) u16 SM[16384];
  gemm_body<0, float, 64, 64, 128>(SM, Xc, Wo, bo, out, blockIdx.x * 64,
                                   blockIdx.y * 64, 1.0f);
}

// ---------------------------------------------------------------------------
// Flash attention (S^T trick, rel-pos). Verbatim r12/r17 attn (74.4 µs,
// best verified): K+V staged via global_load_lds (single buffer), XOR-swizzled
// K, V b64 reads (2-way conflicts ~free per m136), MFMA denominator (ones-row),
// MFMA rel_v epilogue, bias folded into QK C-operand, exp2 with Q prescale.
// relkb is the precomputed bf16 table (cvt_all z=7).
// ---------------------------------------------------------------------------
__global__ __launch_bounds__(256, 6) void attn_kernel(
    const u16* __restrict__ Qg, const u16* __restrict__ Kg,
    const u16* __restrict__ Vtg, const u16* __restrict__ relkb,
    const float* __restrict__ relv, u16* __restrict__ ctx) {
  __shared__ __align__(16) u16 KV[8192];       // K [0,4096), V^T [4096,8192)
  __shared__ __align__(16) u16 qrelJ[64 * 33]; // Q[q]·relk[j] bf16
  __shared__ __align__(16) u16 wsum[64 * 32];  // in-band p, write-once, col31=0

  const int tid = threadIdx.x, lane = tid & 63, wid = tid >> 6;
  const int l15 = lane & 15, l16 = lane >> 4;
  const int bh = blockIdx.x;  // x-fast => all q-tiles of a bh land on one XCD
  const int b = bh >> 4, h = bh & 15;
  const int by = blockIdx.y;
  const int q0 = by * 64;
  const u16* Qb = Qg + (size_t)bh * 2048 * 64;
  const u16* Kb = Kg + (size_t)bh * 2048 * 64;
  const u16* Vtb = Vtg + (size_t)bh * 64 * 2048;  // [d][s]

  const int lrow = lane >> 3;
  const int lchunk = (lane & 7) ^ lrow;
  const int qw = wid * 16;
  const int kq4 = l16 * 4;
  const int qrow = qw + l15;

  // ---- prologue: stage Q into KV, zero wsum ----
#pragma unroll
  for (int i = 0; i < 2; i++) {
    const int rb = qw + i * 8;
    GLOAD_LDS16(Qb + (size_t)(q0 + rb + lrow) * 64 + lchunk * 8, &KV[rb * 64]);
  }
  for (int idx = tid; idx < 1024; idx += 256) ((unsigned int*)wsum)[idx] = 0u;
  __syncthreads();

  // ---- hoist Q fragment ----
  short8 aq[2];
  {
    const int m = qw + l15;
    aq[0] = *(const short8*)&KV[m * 64 + ((l16 ^ (m & 7)) * 8)];
    aq[1] = *(const short8*)&KV[m * 64 + (((4 + l16) ^ (m & 7)) * 8)];
  }
  // ---- qrel GEMM: qrelJ[q][j] = Q[q]·relk[j] ----
  {
    f32x4 qa[3];
#pragma unroll
    for (int nt = 0; nt < 3; nt++) {
      qa[nt] = (f32x4){0.f, 0.f, 0.f, 0.f};
#pragma unroll
      for (int kk = 0; kk < 2; kk++) {
        const short8 bf =
            *(const short8*)(relkb + (nt * 16 + l15) * 64 + kk * 32 + l16 * 8);
        qa[nt] = MFMA16(aq[kk], bf, qa[nt]);
      }
    }
#pragma unroll
    for (int nt = 0; nt < 3; nt++) {
      if (nt < 2 || l15 == 0) {
#pragma unroll
        for (int r = 0; r < 4; r++)
          qrelJ[(qw + kq4 + r) * 33 + nt * 16 + l15] = f2us(qa[nt][r]);
      }
    }
  }
  WAIT_LGKM0();  // aq reads + qrelJ writes drained before KV overwrite / reads
  const float q0r = us2f(qrelJ[qrow * 33 + 0]);
  const float q32r = us2f(qrelJ[qrow * 33 + 32]);
  const f32x4 ebl = (f32x4){q0r, q0r, q0r, q0r};
  const f32x4 ebr = (f32x4){q32r, q32r, q32r, q32r};
  const f32x4 zf = (f32x4){0.f, 0.f, 0.f, 0.f};
  const short4_t ones4 = (short4_t){(short)0x3F80, (short)0x3F80,
                                    (short)0x3F80, (short)0x3F80};

  float wl_p = 0.f, wr_p = 0.f;            // diag-tile partials (VALU)
  f32x4 SL = zf, SR = zf, SD = zf;         // ones-MFMA denominator sums
  f32x4 Oacc[4];
#pragma unroll
  for (int t = 0; t < 4; t++) Oacc[t] = zf;

  // stage K/V tile k0c into LDS (single buffer, two barriers)
  auto stage = [&](int k0c) {
    SBAR();  // all waves done reading previous tile
#pragma unroll
    for (int i = 0; i < 2; i++) {
      const int rb = qw + i * 8;
      GLOAD_LDS16(Kb + (size_t)(k0c + rb + lrow) * 64 + lchunk * 8, &KV[rb * 64]);
    }
#pragma unroll
    for (int i = 0; i < 2; i++) {
      const int rb = qw + i * 8;
      GLOAD_LDS16(Vtb + (size_t)(rb + lrow) * 2048 + k0c + lchunk * 8,
                  &KV[4096 + rb * 64]);
    }
    WAIT_VM0();
    SBAR();  // tile visible to all waves
  };

  // S^T quadrant tn = K·Q^T with C-init (bias pre-folded for off-diag)
  auto qk = [&](int tn, f32x4 cin) -> f32x4 {
    const int n = tn * 16 + l15;
    const short8 bk0 = *(const short8*)&KV[n * 64 + ((l16 ^ (n & 7)) * 8)];
    const short8 bk1 = *(const short8*)&KV[n * 64 + (((4 + l16) ^ (n & 7)) * 8)];
    f32x4 s = MFMA16(bk0, aq[0], cin);
    s = MFMA16(bk1, aq[1], s);
    return s;
  };

  // O^T += V^T · P^T
  auto pvstep = [&](const short4_t* pf) {
    __builtin_amdgcn_s_setprio(1);
#pragma unroll
    for (int td = 0; td < 4; td++) {
      const int row = td * 16 + l15;
      const int rs = row & 7;
#pragma unroll
      for (int kk = 0; kk < 4; kk++) {
        const short4_t vf = *(const short4_t*)&KV[4096 + row * 64 +
                                                  (((kk * 2 + (l16 >> 1)) ^ rs) * 8) +
                                                  (l16 & 1) * 4];
        Oacc[td] = MFMAK16(vf, pf[kk], Oacc[td]);
      }
    }
    __builtin_amdgcn_s_setprio(0);
  };

  // denominator: S += colsum(P) via ones-row MFMA (matrix pipe, no VALU)
  auto psum = [&](const short4_t* pf, f32x4& S) {
#pragma unroll
    for (int kk = 0; kk < 4; kk++) S = MFMAK16(ones4, pf[kk], S);
  };

  // off-diagonal tile body: bias folded into C, no per-score bookkeeping
  auto offdiag = [&](f32x4 ebv, f32x4& S) {
    short4_t pf[4];
#pragma unroll
    for (int tn = 0; tn < 4; tn++) {
      const f32x4 sac = qk(tn, ebv);
      union { unsigned int u[2]; short4_t s; } c;
      c.u[0] = f2us2(exp2fast(sac[0]), exp2fast(sac[1]));
      c.u[1] = f2us2(exp2fast(sac[2]), exp2fast(sac[3]));
      pf[tn] = c.s;
    }
    pvstep(pf);
    psum(pf, S);
  };

  // diagonal tile body: per-element clamp/bias, in-band p to wsum
  auto diag = [&](int k0) {
    short4_t pf[4];
#pragma unroll
    for (int tn = 0; tn < 4; tn++) {
      const f32x4 sac = qk(tn, zf);
      float pv4[4];
#pragma unroll
      for (int r = 0; r < 4; r++) {
        const int kg = k0 + tn * 16 + kq4 + r;
        const int dlt = kg - (q0 + qrow);
        const int jj = (dlt < -16 ? -16 : (dlt > 16 ? 16 : dlt)) + 16;
        const float p = exp2fast(sac[r] + us2f(qrelJ[qrow * 33 + jj]));
        pv4[r] = p;
        if (dlt <= -16) wl_p += p;
        else if (dlt >= 16) wr_p += p;
        else wsum[qrow * 32 + (dlt + 15)] = f2us(p);
      }
      union { unsigned int u[2]; short4_t s; } c;
      c.u[0] = f2us2(pv4[0], pv4[1]);
      c.u[1] = f2us2(pv4[2], pv4[3]);
      pf[tn] = c.s;
    }
    pvstep(pf);
    psum(pf, SD);
  };

  // ---- main loop, split into left / diag / right tile ranges ----
  const int dlo = (by >= 1) ? by - 1 : 0;        // first diag tile
  const int dhi = (by + 2 <= 32) ? by + 2 : 32;  // one past last diag tile
  for (int kt = 0; kt < dlo; ++kt) { stage(kt * 64); offdiag(ebl, SL); }
  for (int kt = dlo; kt < dhi; ++kt) { stage(kt * 64); diag(kt * 64); }
  for (int kt = dhi; kt < 32; ++kt) { stage(kt * 64); offdiag(ebr, SR); }

  // ---- epilogue ----
  wl_p += __shfl_xor(wl_p, 16); wl_p += __shfl_xor(wl_p, 32);
  wr_p += __shfl_xor(wr_p, 16); wr_p += __shfl_xor(wr_p, 32);
  const float l_total = SL[0] + SR[0] + SD[0];   // full col sums, no shuffle
  const float linv = 1.f / l_total;
  const float wl = (SL[0] + wl_p) * linv;
  const float wr = (SR[0] + wr_p) * linv;

  // rel_v in-band term as a matmul: O^T[d][q] += sum_c relv[c+1][d]*wsum[q][c]
  {
    short4_t relf[4][2];  // A: rows d=td*16+l15, k = kk*16 + l16*4 + e
#pragma unroll
    for (int td = 0; td < 4; td++)
#pragma unroll
      for (int kk = 0; kk < 2; kk++) {
        const int jb = kk * 16 + l16 * 4 + 1;  // relv rows 1..32, all valid
        const int d = td * 16 + l15;
        union { unsigned int u[2]; short4_t s; } c;
        c.u[0] = f2us2(relv[(jb + 0) * 64 + d], relv[(jb + 1) * 64 + d]);
        c.u[1] = f2us2(relv[(jb + 2) * 64 + d], relv[(jb + 3) * 64 + d]);
        relf[td][kk] = c.s;
      }
    WAIT_LGKM0();  // wave's own wsum ds_writes drained before re-read
    short4_t wfrag[2];    // B: col q=qw+l15, k = kk*16 + l16*4 + e (col31=0)
#pragma unroll
    for (int kk = 0; kk < 2; kk++)
      wfrag[kk] = *(const short4_t*)&wsum[qrow * 32 + kk * 16 + l16 * 4];
#pragma unroll
    for (int td = 0; td < 4; td++)
#pragma unroll
      for (int kk = 0; kk < 2; kk++)
        Oacc[td] = MFMAK16(relf[td][kk], wfrag[kk], Oacc[td]);
  }

#pragma unroll
  for (int td = 0; td < 4; td++) {
    const f32x4 rv0 = *(const f32x4*)&relv[td * 16 + kq4];
    const f32x4 rv32 = *(const f32x4*)&relv[32 * 64 + td * 16 + kq4];
#pragma unroll
    for (int r = 0; r < 4; r++)
      Oacc[td][r] = Oacc[td][r] * linv + wl * rv0[r] + wr * rv32[r];
  }

  SBAR();  // all waves past their last KV reads -> KV free for O tile
  // O tile [q 64][d 64] stride 72 u16 (b128-aligned), wave-private q rows
#pragma unroll
  for (int td = 0; td < 4; td++) {
    unsigned int o[2];
    o[0] = f2us2(Oacc[td][0], Oacc[td][1]);
    o[1] = f2us2(Oacc[td][2], Oacc[td][3]);
    *(short4_t*)&KV[qrow * 72 + td * 16 + kq4] = *(short4_t*)o;
  }
  WAIT_LGKM0();
  SBAR();
#pragma unroll
  for (int i = 0; i < 2; i++) {
    const int idx = tid + i * 256;  // 512 chunks of 8 u16
    const int q = idx >> 3, sc = idx & 7;
    const short8 v = *(const short8*)&KV[q * 72 + sc * 8];
    *(short8*)&ctx[((size_t)b * 2048 + q0 + q) * 1024 + h * 64 + sc * 8] = v;
  }
}

// ---------------------------------------------------------------------------
extern "C" void kernel_launch(void* const* d_in, const int* in_sizes, int n_in,
                              void* d_out, int out_size, void* d_ws, size_t ws_size,
                              hipStream_t stream) {
  u16* qb = (u16*)d_ws;                 // [32][2048][64]
  u16* kb = qb + 4194304;               // [32][2048][64]
  u16* vtb = kb + 4194304;              // [32][64][2048]
  u16* ctx = vtb + 4194304;             // [2][2048][1024]
  u16* Xq = ctx + 4194304;
  u16* Xk = Xq + 4194304;
  u16* Xv = Xk + 4194304;
  u16* Wqb = Xv + 4194304;
  u16* Wkb = Wqb + 1048576;
  u16* Wvb = Wkb + 1048576;
  u16* Wob = Wvb + 1048576;
  u16* relkb = Wob + 1048576;           // [64][64] bf16

  const float* bq = (const float*)d_in[4];
  const float* bk = (const float*)d_in[6];
  const float* bv = (const float*)d_in[8];
  const float* bo = (const float*)d_in[10];
  const float* relk = (const float*)d_in[11];
  const float* relv = (const float*)d_in[12];

  dim3 blk(256);
  cvt_all_kernel<<<dim3(2048, 1, 8), blk, 0, stream>>>(
      (const float*)d_in[0], (const float*)d_in[1], (const float*)d_in[2],
      (const float*)d_in[3], (const float*)d_in[5], (const float*)d_in[7],
      (const float*)d_in[9], relk, Xq, Xk, Xv, Wqb, Wkb, Wvb, Wob, relkb);
  qkv_kernel<<<dim3(32, 8, 3), blk, 0, stream>>>(Xq, Xk, Xv, Wqb, Wkb, Wvb, bq,
                                                 bk, bv, qb, kb, vtb);
  attn_kernel<<<dim3(32, 32), blk, 0, stream>>>(qb, kb, vtb, relkb, relv, ctx);
  oproj_kernel<<<dim3(64, 16), blk, 0, stream>>>(ctx, Wob, bo, (float*)d_out);
}

// Round 11
// 240.263 us; speedup vs baseline: 1.1624x; 1.0132x over previous
//
#include <hip/hip_runtime.h>
#include <hip/hip_bf16.h>

typedef unsigned short u16;
typedef __attribute__((ext_vector_type(8))) short short8;
typedef __attribute__((ext_vector_type(4))) short short4_t;
typedef __attribute__((ext_vector_type(4))) float f32x4;

#define MFMA16(a, b, c) __builtin_amdgcn_mfma_f32_16x16x32_bf16((a), (b), (c), 0, 0, 0)

#if __has_builtin(__builtin_amdgcn_mfma_f32_16x16x16bf16_1k)
#define MFMAK16(a, b, c) __builtin_amdgcn_mfma_f32_16x16x16bf16_1k((a), (b), (c), 0, 0, 0)
#elif __has_builtin(__builtin_amdgcn_mfma_f32_16x16x16_bf16)
#define MFMAK16(a, b, c) __builtin_amdgcn_mfma_f32_16x16x16_bf16((a), (b), (c), 0, 0, 0)
#else
__device__ __forceinline__ f32x4 mfmak16_asm(short4_t a, short4_t b, f32x4 c) {
  asm("v_mfma_f32_16x16x16_bf16 %0, %1, %2, %0" : "+v"(c) : "v"(a), "v"(b));
  return c;
}
#define MFMAK16(a, b, c) mfmak16_asm((a), (b), (c))
#endif

#define GLOAD_LDS16(gp, lp)                                          \
  __builtin_amdgcn_global_load_lds(                                  \
      (const __attribute__((address_space(1))) void*)(gp),           \
      (__attribute__((address_space(3))) void*)(lp), 16, 0, 0)
#define SBAR() asm volatile("s_barrier" ::: "memory")
#define WAIT_LGKM0() asm volatile("s_waitcnt lgkmcnt(0)" ::: "memory")
#define WAIT_VM0() asm volatile("s_waitcnt vmcnt(0)" ::: "memory")

#define LOG2E 1.44269504088896340736f

__device__ __forceinline__ float us2f(u16 u) {
  union { unsigned int i; float f; } c; c.i = ((unsigned int)u) << 16; return c.f;
}
__device__ __forceinline__ u16 f2us(float f) {
  union { float f; unsigned int i; } c; c.f = f;
  return (u16)((c.i + 0x7fffu + ((c.i >> 16) & 1u)) >> 16);
}
__device__ __forceinline__ unsigned int f2us2(float a, float b) {
  union { __hip_bfloat162 h; unsigned int u; } c;
  c.h = __float22bfloat162_rn(float2{a, b});
  return c.u;
}
__device__ __forceinline__ float exp2fast(float x) {
#if __has_builtin(__builtin_amdgcn_exp2f)
  return __builtin_amdgcn_exp2f(x);
#else
  return exp2f(x);
#endif
}

// ---------------------------------------------------------------------------
// Fused f32 -> bf16 convert for the 7 big tensors + relk table (z=7).
// Separate pass on purpose: reads f32 ONCE at streaming BW. Fusing the
// conversion into the consumers lost twice (r15 qkv: latency-bound panel
// re-fetch; r16 relk: scattered loads on the serial prologue path, +10 µs).
// ---------------------------------------------------------------------------
__global__ __launch_bounds__(256) void cvt_all_kernel(
    const float* x0, const float* x1, const float* x2, const float* w0,
    const float* w1, const float* w2, const float* w3, const float* relk,
    u16* y0, u16* y1, u16* y2, u16* z0, u16* z1, u16* z2, u16* z3,
    u16* relkb) {
  const int z = blockIdx.z;
  if (z == 7) {
    // relk [33][64] f32 -> relkb [64][64] bf16 (rows 33..63 zero)
    const int i = (blockIdx.x * 256 + threadIdx.x) * 8;
    if (i < 4096) {
      if (i < 2112) {
        const float4 a = *(const float4*)(relk + i);
        const float4 b = *(const float4*)(relk + i + 4);
        unsigned int o[4];
        o[0] = f2us2(a.x, a.y); o[1] = f2us2(a.z, a.w);
        o[2] = f2us2(b.x, b.y); o[3] = f2us2(b.z, b.w);
        *(uint4*)(relkb + i) = *(uint4*)o;
      } else {
        uint4 zz = {0u, 0u, 0u, 0u};
        *(uint4*)(relkb + i) = zz;
      }
    }
    return;
  }
  const float* src; u16* dst; int n;
  switch (z) {
    case 0: src = x0; dst = y0; n = 4194304; break;
    case 1: src = x1; dst = y1; n = 4194304; break;
    case 2: src = x2; dst = y2; n = 4194304; break;
    case 3: src = w0; dst = z0; n = 1048576; break;
    case 4: src = w1; dst = z1; n = 1048576; break;
    case 5: src = w2; dst = z2; n = 1048576; break;
    default: src = w3; dst = z3; n = 1048576; break;
  }
  const int i = (blockIdx.x * 256 + threadIdx.x) * 8;
  if (i < n) {
    const float4 a = *(const float4*)(src + i);
    const float4 b = *(const float4*)(src + i + 4);
    unsigned int o[4];
    o[0] = f2us2(a.x, a.y); o[1] = f2us2(a.z, a.w);
    o[2] = f2us2(b.x, b.y); o[3] = f2us2(b.z, b.w);
    *(uint4*)(dst + i) = *(uint4*)o;
  }
}

// ---------------------------------------------------------------------------
// GEMM: Y = (X @ W^T + bias) * oscale.  BM x BN block tile, 4 waves (2x2),
// BK-deep K-steps (BK=64 or 128). BK=64 path byte-identical to verified r12.
// MODE 0: f32 row-major [4096][1024].  MODE 1: u16 [bh][s][d].  MODE 2:
// u16 [bh][d][s].  Modes 1/2 (BM=BN=128, BK=64 only) use an LDS transpose.
// ---------------------------------------------------------------------------
template <int MODE, typename OUT, int BM, int BN, int BK>
__device__ __forceinline__ void gemm_body(u16* __restrict__ SM,
                                          const u16* __restrict__ X,
                                          const u16* __restrict__ W,
                                          const float* __restrict__ bias,
                                          OUT* __restrict__ Y, int row0, int col0,
                                          float oscale) {
  constexpr int TM = BM / 32, TN = BN / 32;  // 16-row tiles per wave
  constexpr int CH = BK / 8;                 // 16B chunks per row
  constexpr int RPG = 64 / CH;               // rows per gload instruction
  constexpr int NGA = BM / (4 * RPG);        // A gloads per wave per k-step
  constexpr int NGB = BN / (4 * RPG);        // B gloads per wave per k-step
  u16* As = SM;              // [BM][BK]
  u16* Bs = SM + BM * BK;    // [BN][BK]
  const int tid = threadIdx.x;
  const int lane = tid & 63;
  const int wid = tid >> 6;
  const int wm = wid >> 1, wn = wid & 1;
  const int l15 = lane & 15, l16 = lane >> 4;
  const int lrow = lane / CH;   // row within gload group
  const int lch = lane % CH;    // chunk within row

  f32x4 acc[TM][TN];
#pragma unroll
  for (int i = 0; i < TM; i++)
#pragma unroll
    for (int j = 0; j < TN; j++) acc[i][j] = (f32x4){0.f, 0.f, 0.f, 0.f};

  for (int k0 = 0; k0 < 1024; k0 += BK) {
#pragma unroll
    for (int i = 0; i < NGA; i++) {
      const int rb = (wid * NGA + i) * RPG;
      const int row = rb + lrow;
      GLOAD_LDS16(X + (size_t)(row0 + row) * 1024 + k0 + ((lch ^ (row & 7)) * 8),
                  &As[rb * BK]);
    }
#pragma unroll
    for (int i = 0; i < NGB; i++) {
      const int rb = (wid * NGB + i) * RPG;
      const int row = rb + lrow;
      GLOAD_LDS16(W + (size_t)(col0 + row) * 1024 + k0 + ((lch ^ (row & 7)) * 8),
                  &Bs[rb * BK]);
    }
    __syncthreads();
#pragma unroll
    for (int kk = 0; kk < BK / 32; kk++) {
      const int ch = kk * 4 + l16;
      short8 af[TM], bfr[TN];
#pragma unroll
      for (int t = 0; t < TM; t++) {
        const int m = wm * (BM / 2) + t * 16 + l15;
        af[t] = *(const short8*)&As[m * BK + ((ch ^ (m & 7)) * 8)];
      }
#pragma unroll
      for (int t = 0; t < TN; t++) {
        const int n = wn * (BN / 2) + t * 16 + l15;
        bfr[t] = *(const short8*)&Bs[n * BK + ((ch ^ (n & 7)) * 8)];
      }
#pragma unroll
      for (int tm = 0; tm < TM; tm++)
#pragma unroll
        for (int tn = 0; tn < TN; tn++)
          acc[tm][tn] = MFMA16(af[tm], bfr[tn], acc[tm][tn]);
    }
    __syncthreads();
  }

  if (MODE == 0) {
#pragma unroll
    for (int tn = 0; tn < TN; tn++) {
      const int col = col0 + wn * (BN / 2) + tn * 16 + l15;
      const float bv = bias[col];
#pragma unroll
      for (int tm = 0; tm < TM; tm++) {
        const int rowb = row0 + wm * (BM / 2) + tm * 16 + l16 * 4;
#pragma unroll
        for (int r = 0; r < 4; r++)
          Y[(size_t)(rowb + r) * 1024 + col] = (OUT)(acc[tm][tn][r] + bv);
      }
    }
  } else {
    // LDS-transpose epilogue (BM=BN=128 only), two 64-row passes.
    u16* T = SM;
    const int bb = row0 >> 11;
    const int sbase = row0 & 2047;
#pragma unroll
    for (int pass = 0; pass < 2; pass++) {
      __syncthreads();
      if (wm == pass) {
#pragma unroll
        for (int tn = 0; tn < TN; tn++) {
          const int coll = wn * 64 + tn * 16 + l15;
          const float bv = bias[col0 + coll];
#pragma unroll
          for (int tm = 0; tm < TM; tm++) {
            if (MODE == 1) {
#pragma unroll
              for (int r = 0; r < 4; r++)
                T[(tm * 16 + l16 * 4 + r) * 136 + coll] = f2us((acc[tm][tn][r] + bv) * oscale);
            } else {
              unsigned int o[2];
              o[0] = f2us2(acc[tm][tn][0] + bv, acc[tm][tn][1] + bv);
              o[1] = f2us2(acc[tm][tn][2] + bv, acc[tm][tn][3] + bv);
              *(short4_t*)&T[coll * 72 + tm * 16 + l16 * 4] = *(short4_t*)o;
            }
          }
        }
      }
      __syncthreads();
      if (MODE == 1) {
#pragma unroll
        for (int i = 0; i < 8; i++) {
          const int idx = tid + i * 256;           // 2048 chunks of 4 u16
          const int srow = idx >> 5, c4 = idx & 31;
          const short4_t v = *(const short4_t*)&T[srow * 136 + c4 * 4];
          const int col = col0 + c4 * 4;
          const int hh = col >> 6, dd = col & 63;
          const int s = sbase + pass * 64 + srow;
          *(short4_t*)&((u16*)Y)[(((size_t)(bb * 16 + hh)) * 2048 + s) * 64 + dd] = v;
        }
      } else {
#pragma unroll
        for (int i = 0; i < 4; i++) {
          const int idx = tid + i * 256;           // 1024 chunks of 8 u16
          const int cl = idx >> 3, sc = idx & 7;
          const short8 v = *(const short8*)&T[cl * 72 + sc * 8];
          const int col = col0 + cl;
          const int hh = col >> 6, dd = col & 63;
          const int s = sbase + pass * 64 + sc * 8;
          *(short8*)&((u16*)Y)[(((size_t)(bb * 16 + hh)) * 64 + dd) * 2048 + s] = v;
        }
      }
    }
  }
}

__global__ __launch_bounds__(256) void qkv_kernel(
    const u16* Xq, const u16* Xk, const u16* Xv, const u16* Wq, const u16* Wk,
    const u16* Wv, const float* bq, const float* bk, const float* bv, u16* Yq,
    u16* Yk, u16* Yv) {
  __shared__ __align__(16) u16 SM[16384];
  const int z = blockIdx.z;
  const u16* X = z == 0 ? Xq : (z == 1 ? Xk : Xv);
  const u16* W = z == 0 ? Wq : (z == 1 ? Wk : Wv);
  const float* bi = z == 0 ? bq : (z == 1 ? bk : bv);
  u16* Y = z == 0 ? Yq : (z == 1 ? Yk : Yv);
  if (z == 2)
    gemm_body<2, u16, 128, 128, 64>(SM, X, W, bi, Y, blockIdx.x * 128,
                                    blockIdx.y * 128, 1.0f);
  else
    gemm_body<1, u16, 128, 128, 64>(SM, X, W, bi, Y, blockIdx.x * 128,
                                    blockIdx.y * 128,
                                    z == 0 ? LOG2E : 1.0f);  // fold 1/ln2 into Q
}

// oproj: 64x64 tiles (1024 blocks = 4/CU), BK=128 (r18: halves sync points).
__global__ __launch_bounds__(256) void oproj_kernel(const u16* Xc, const u16* Wo,
                                                    const float* bo, float* out) {
  __shared__ __align__(16) u16 SM[16384];
  gemm_body<0, float, 64, 64, 128>(SM, Xc, Wo, bo, out, blockIdx.x * 64,
                                   blockIdx.y * 64, 1.0f);
}

// ---------------------------------------------------------------------------
// Flash attention (S^T trick, rel-pos). r19: 2 q-tiles per block (8 waves,
// 512 threads) sharing ONE K/V staging stream. Per unit compute: staging
// instructions, barriers, and vmcnt(0) drains HALVE; K/V HBM fetch halves
// (16 q-blocks re-read per bh instead of 32). Per-wave code is r12-identical
// (qrow = wid*16+l15 now spans 128 rows); tile classification is a
// wave-uniform branch on the wave's own q0w. O-store: two 64-row passes.
// ---------------------------------------------------------------------------
__global__ __launch_bounds__(512, 4) void attn_kernel(
    const u16* __restrict__ Qg, const u16* __restrict__ Kg,
    const u16* __restrict__ Vtg, const u16* __restrict__ relkb,
    const float* __restrict__ relv, u16* __restrict__ ctx) {
  __shared__ __align__(16) u16 KV[8192];        // K [0,4096), V^T [4096,8192)
  __shared__ __align__(16) u16 qrelJ[128 * 33]; // Q[q]·relk[j] bf16
  __shared__ __align__(16) u16 wsum[128 * 32];  // in-band p, write-once, col31=0

  const int tid = threadIdx.x, lane = tid & 63, wid = tid >> 6;  // wid 0..7
  const int l15 = lane & 15, l16 = lane >> 4;
  const int bh = blockIdx.x;  // x-fast => all q-tiles of a bh land on one XCD
  const int b = bh >> 4, h = bh & 15;
  const int by = blockIdx.y;            // 0..15
  const int q0b = by * 128;             // block q base (128 rows)
  const int qt = wid >> 2;              // q-tile 0/1 within block
  const int q0w = q0b + qt * 64;        // wave's q-tile base (classification)
  const u16* Qb = Qg + (size_t)bh * 2048 * 64;
  const u16* Kb = Kg + (size_t)bh * 2048 * 64;
  const u16* Vtb = Vtg + (size_t)bh * 64 * 2048;  // [d][s]

  const int lrow = lane >> 3;
  const int lchunk = (lane & 7) ^ lrow;
  const int qw16 = wid * 16;            // row base in 128-row block space
  const int kq4 = l16 * 4;
  const int qrow = qw16 + l15;          // 0..127

  // ---- prologue: stage 128 Q rows into KV, zero wsum ----
#pragma unroll
  for (int i = 0; i < 2; i++) {
    const int rb = qw16 + i * 8;
    GLOAD_LDS16(Qb + (size_t)(q0b + rb + lrow) * 64 + lchunk * 8, &KV[rb * 64]);
  }
  for (int idx = tid; idx < 2048; idx += 512) ((unsigned int*)wsum)[idx] = 0u;
  __syncthreads();

  // ---- hoist Q fragment (wave's 16 rows of the 128-row staging) ----
  short8 aq[2];
  {
    const int m = qrow;
    aq[0] = *(const short8*)&KV[m * 64 + ((l16 ^ (m & 7)) * 8)];
    aq[1] = *(const short8*)&KV[m * 64 + (((4 + l16) ^ (m & 7)) * 8)];
  }
  // ---- qrel GEMM: qrelJ[q][j] = Q[q]·relk[j] ----
  {
    f32x4 qa[3];
#pragma unroll
    for (int nt = 0; nt < 3; nt++) {
      qa[nt] = (f32x4){0.f, 0.f, 0.f, 0.f};
#pragma unroll
      for (int kk = 0; kk < 2; kk++) {
        const short8 bf =
            *(const short8*)(relkb + (nt * 16 + l15) * 64 + kk * 32 + l16 * 8);
        qa[nt] = MFMA16(aq[kk], bf, qa[nt]);
      }
    }
#pragma unroll
    for (int nt = 0; nt < 3; nt++) {
      if (nt < 2 || l15 == 0) {
#pragma unroll
        for (int r = 0; r < 4; r++)
          qrelJ[(qw16 + kq4 + r) * 33 + nt * 16 + l15] = f2us(qa[nt][r]);
      }
    }
  }
  WAIT_LGKM0();  // aq reads + qrelJ writes drained before KV overwrite / reads
  const float q0r = us2f(qrelJ[qrow * 33 + 0]);
  const float q32r = us2f(qrelJ[qrow * 33 + 32]);
  const f32x4 ebl = (f32x4){q0r, q0r, q0r, q0r};
  const f32x4 ebr = (f32x4){q32r, q32r, q32r, q32r};
  const f32x4 zf = (f32x4){0.f, 0.f, 0.f, 0.f};
  const short4_t ones4 = (short4_t){(short)0x3F80, (short)0x3F80,
                                    (short)0x3F80, (short)0x3F80};

  float wl_p = 0.f, wr_p = 0.f;            // diag-tile partials (VALU)
  f32x4 SL = zf, SR = zf, SD = zf;         // ones-MFMA denominator sums
  f32x4 Oacc[4];
#pragma unroll
  for (int t = 0; t < 4; t++) Oacc[t] = zf;

  // stage K/V tile k0c into LDS (single buffer; 8 waves, 1 gload each for
  // K and V -> half the staging instructions per compute vs 4-wave blocks)
  auto stage = [&](int k0c) {
    SBAR();  // all waves done reading previous tile
    {
      const int rb = wid * 8;
      GLOAD_LDS16(Kb + (size_t)(k0c + rb + lrow) * 64 + lchunk * 8, &KV[rb * 64]);
      GLOAD_LDS16(Vtb + (size_t)(rb + lrow) * 2048 + k0c + lchunk * 8,
                  &KV[4096 + rb * 64]);
    }
    WAIT_VM0();
    SBAR();  // tile visible to all waves
  };

  // S^T quadrant tn = K·Q^T with C-init (bias pre-folded for off-diag)
  auto qk = [&](int tn, f32x4 cin) -> f32x4 {
    const int n = tn * 16 + l15;
    const short8 bk0 = *(const short8*)&KV[n * 64 + ((l16 ^ (n & 7)) * 8)];
    const short8 bk1 = *(const short8*)&KV[n * 64 + (((4 + l16) ^ (n & 7)) * 8)];
    f32x4 s = MFMA16(bk0, aq[0], cin);
    s = MFMA16(bk1, aq[1], s);
    return s;
  };

  // O^T += V^T · P^T
  auto pvstep = [&](const short4_t* pf) {
    __builtin_amdgcn_s_setprio(1);
#pragma unroll
    for (int td = 0; td < 4; td++) {
      const int row = td * 16 + l15;
      const int rs = row & 7;
#pragma unroll
      for (int kk = 0; kk < 4; kk++) {
        const short4_t vf = *(const short4_t*)&KV[4096 + row * 64 +
                                                  (((kk * 2 + (l16 >> 1)) ^ rs) * 8) +
                                                  (l16 & 1) * 4];
        Oacc[td] = MFMAK16(vf, pf[kk], Oacc[td]);
      }
    }
    __builtin_amdgcn_s_setprio(0);
  };

  // denominator: S += colsum(P) via ones-row MFMA (matrix pipe, no VALU)
  auto psum = [&](const short4_t* pf, f32x4& S) {
#pragma unroll
    for (int kk = 0; kk < 4; kk++) S = MFMAK16(ones4, pf[kk], S);
  };

  // off-diagonal tile body: bias folded into C, no per-score bookkeeping
  auto offdiag = [&](f32x4 ebv, f32x4& S) {
    short4_t pf[4];
#pragma unroll
    for (int tn = 0; tn < 4; tn++) {
      const f32x4 sac = qk(tn, ebv);
      union { unsigned int u[2]; short4_t s; } c;
      c.u[0] = f2us2(exp2fast(sac[0]), exp2fast(sac[1]));
      c.u[1] = f2us2(exp2fast(sac[2]), exp2fast(sac[3]));
      pf[tn] = c.s;
    }
    pvstep(pf);
    psum(pf, S);
  };

  // diagonal tile body: per-element clamp/bias, in-band p to wsum
  auto diag = [&](int k0) {
    short4_t pf[4];
#pragma unroll
    for (int tn = 0; tn < 4; tn++) {
      const f32x4 sac = qk(tn, zf);
      float pv4[4];
#pragma unroll
      for (int r = 0; r < 4; r++) {
        const int kg = k0 + tn * 16 + kq4 + r;
        const int dlt = kg - (q0b + qrow);
        const int jj = (dlt < -16 ? -16 : (dlt > 16 ? 16 : dlt)) + 16;
        const float p = exp2fast(sac[r] + us2f(qrelJ[qrow * 33 + jj]));
        pv4[r] = p;
        if (dlt <= -16) wl_p += p;
        else if (dlt >= 16) wr_p += p;
        else wsum[qrow * 32 + (dlt + 15)] = f2us(p);
      }
      union { unsigned int u[2]; short4_t s; } c;
      c.u[0] = f2us2(pv4[0], pv4[1]);
      c.u[1] = f2us2(pv4[2], pv4[3]);
      pf[tn] = c.s;
    }
    pvstep(pf);
    psum(pf, SD);
  };

  // ---- main loop: per-wave (uniform) tile classification ----
  for (int kt = 0; kt < 32; ++kt) {
    const int k0 = kt * 64;
    stage(k0);
    if (k0 + 79 <= q0w) {
      offdiag(ebl, SL);
    } else if (k0 >= q0w + 79) {
      offdiag(ebr, SR);
    } else {
      diag(k0);
    }
  }

  // ---- epilogue ----
  wl_p += __shfl_xor(wl_p, 16); wl_p += __shfl_xor(wl_p, 32);
  wr_p += __shfl_xor(wr_p, 16); wr_p += __shfl_xor(wr_p, 32);
  const float l_total = SL[0] + SR[0] + SD[0];   // full col sums, no shuffle
  const float linv = 1.f / l_total;
  const float wl = (SL[0] + wl_p) * linv;
  const float wr = (SR[0] + wr_p) * linv;

  // rel_v in-band term as a matmul: O^T[d][q] += sum_c relv[c+1][d]*wsum[q][c]
  {
    short4_t relf[4][2];  // A: rows d=td*16+l15, k = kk*16 + l16*4 + e
#pragma unroll
    for (int td = 0; td < 4; td++)
#pragma unroll
      for (int kk = 0; kk < 2; kk++) {
        const int jb = kk * 16 + l16 * 4 + 1;  // relv rows 1..32, all valid
        const int d = td * 16 + l15;
        union { unsigned int u[2]; short4_t s; } c;
        c.u[0] = f2us2(relv[(jb + 0) * 64 + d], relv[(jb + 1) * 64 + d]);
        c.u[1] = f2us2(relv[(jb + 2) * 64 + d], relv[(jb + 3) * 64 + d]);
        relf[td][kk] = c.s;
      }
    WAIT_LGKM0();  // wave's own wsum ds_writes drained before re-read
    short4_t wfrag[2];    // B: col q=qrow, k = kk*16 + l16*4 + e (col31=0)
#pragma unroll
    for (int kk = 0; kk < 2; kk++)
      wfrag[kk] = *(const short4_t*)&wsum[qrow * 32 + kk * 16 + l16 * 4];
#pragma unroll
    for (int td = 0; td < 4; td++)
#pragma unroll
      for (int kk = 0; kk < 2; kk++)
        Oacc[td] = MFMAK16(relf[td][kk], wfrag[kk], Oacc[td]);
  }

#pragma unroll
  for (int td = 0; td < 4; td++) {
    const f32x4 rv0 = *(const f32x4*)&relv[td * 16 + kq4];
    const f32x4 rv32 = *(const f32x4*)&relv[32 * 64 + td * 16 + kq4];
#pragma unroll
    for (int r = 0; r < 4; r++)
      Oacc[td][r] = Oacc[td][r] * linv + wl * rv0[r] + wr * rv32[r];
  }

  SBAR();  // all waves past their last KV reads -> KV free for O tile
  // O store: two 64-row passes through KV ([64][72] u16, b128-aligned)
#pragma unroll
  for (int pass = 0; pass < 2; pass++) {
    if (qt == pass) {
      const int orow = (wid & 3) * 16 + l15;  // 0..63 within this q-tile
#pragma unroll
      for (int td = 0; td < 4; td++) {
        unsigned int o[2];
        o[0] = f2us2(Oacc[td][0], Oacc[td][1]);
        o[1] = f2us2(Oacc[td][2], Oacc[td][3]);
        *(short4_t*)&KV[orow * 72 + td * 16 + kq4] = *(short4_t*)o;
      }
      WAIT_LGKM0();
    }
    SBAR();
    {
      const int q = tid >> 3, sc = tid & 7;  // 512 chunks of 8 u16
      const short8 v = *(const short8*)&KV[q * 72 + sc * 8];
      *(short8*)&ctx[((size_t)b * 2048 + q0b + pass * 64 + q) * 1024 + h * 64 +
                     sc * 8] = v;
    }
    SBAR();  // reads done before next pass overwrites KV
  }
}

// ---------------------------------------------------------------------------
extern "C" void kernel_launch(void* const* d_in, const int* in_sizes, int n_in,
                              void* d_out, int out_size, void* d_ws, size_t ws_size,
                              hipStream_t stream) {
  u16* qb = (u16*)d_ws;                 // [32][2048][64]
  u16* kb = qb + 4194304;               // [32][2048][64]
  u16* vtb = kb + 4194304;              // [32][64][2048]
  u16* ctx = vtb + 4194304;             // [2][2048][1024]
  u16* Xq = ctx + 4194304;
  u16* Xk = Xq + 4194304;
  u16* Xv = Xk + 4194304;
  u16* Wqb = Xv + 4194304;
  u16* Wkb = Wqb + 1048576;
  u16* Wvb = Wkb + 1048576;
  u16* Wob = Wvb + 1048576;
  u16* relkb = Wob + 1048576;           // [64][64] bf16

  const float* bq = (const float*)d_in[4];
  const float* bk = (const float*)d_in[6];
  const float* bv = (const float*)d_in[8];
  const float* bo = (const float*)d_in[10];
  const float* relk = (const float*)d_in[11];
  const float* relv = (const float*)d_in[12];

  dim3 blk(256);
  cvt_all_kernel<<<dim3(2048, 1, 8), blk, 0, stream>>>(
      (const float*)d_in[0], (const float*)d_in[1], (const float*)d_in[2],
      (const float*)d_in[3], (const float*)d_in[5], (const float*)d_in[7],
      (const float*)d_in[9], relk, Xq, Xk, Xv, Wqb, Wkb, Wvb, Wob, relkb);
  qkv_kernel<<<dim3(32, 8, 3), blk, 0, stream>>>(Xq, Xk, Xv, Wqb, Wkb, Wvb, bq,
                                                 bk, bv, qb, kb, vtb);
  attn_kernel<<<dim3(32, 16), dim3(512), 0, stream>>>(qb, kb, vtb, relkb, relv,
                                                      ctx);
  oproj_kernel<<<dim3(64, 16), blk, 0, stream>>>(ctx, Wob, bo, (float*)d_out);
}

// Round 12
// 238.554 us; speedup vs baseline: 1.1707x; 1.0072x over previous
//
#include <hip/hip_runtime.h>
#include <hip/hip_bf16.h>

typedef unsigned short u16;
typedef __attribute__((ext_vector_type(8))) short short8;
typedef __attribute__((ext_vector_type(4))) short short4_t;
typedef __attribute__((ext_vector_type(4))) float f32x4;

#define MFMA16(a, b, c) __builtin_amdgcn_mfma_f32_16x16x32_bf16((a), (b), (c), 0, 0, 0)

#if __has_builtin(__builtin_amdgcn_mfma_f32_16x16x16bf16_1k)
#define MFMAK16(a, b, c) __builtin_amdgcn_mfma_f32_16x16x16bf16_1k((a), (b), (c), 0, 0, 0)
#elif __has_builtin(__builtin_amdgcn_mfma_f32_16x16x16_bf16)
#define MFMAK16(a, b, c) __builtin_amdgcn_mfma_f32_16x16x16_bf16((a), (b), (c), 0, 0, 0)
#else
__device__ __forceinline__ f32x4 mfmak16_asm(short4_t a, short4_t b, f32x4 c) {
  asm("v_mfma_f32_16x16x16_bf16 %0, %1, %2, %0" : "+v"(c) : "v"(a), "v"(b));
  return c;
}
#define MFMAK16(a, b, c) mfmak16_asm((a), (b), (c))
#endif

#define GLOAD_LDS16(gp, lp)                                          \
  __builtin_amdgcn_global_load_lds(                                  \
      (const __attribute__((address_space(1))) void*)(gp),           \
      (__attribute__((address_space(3))) void*)(lp), 16, 0, 0)
#define SBAR() asm volatile("s_barrier" ::: "memory")
#define WAIT_LGKM0() asm volatile("s_waitcnt lgkmcnt(0)" ::: "memory")
#define WAIT_VM0() asm volatile("s_waitcnt vmcnt(0)" ::: "memory")

#define LOG2E 1.44269504088896340736f

__device__ __forceinline__ float us2f(u16 u) {
  union { unsigned int i; float f; } c; c.i = ((unsigned int)u) << 16; return c.f;
}
__device__ __forceinline__ u16 f2us(float f) {
  union { float f; unsigned int i; } c; c.f = f;
  return (u16)((c.i + 0x7fffu + ((c.i >> 16) & 1u)) >> 16);
}
__device__ __forceinline__ unsigned int f2us2(float a, float b) {
  union { __hip_bfloat162 h; unsigned int u; } c;
  c.h = __float22bfloat162_rn(float2{a, b});
  return c.u;
}
__device__ __forceinline__ float exp2fast(float x) {
#if __has_builtin(__builtin_amdgcn_exp2f)
  return __builtin_amdgcn_exp2f(x);
#else
  return exp2f(x);
#endif
}

// ---------------------------------------------------------------------------
// Fused f32 -> bf16 convert for the 7 big tensors + relk table (z=7).
// Separate pass on purpose: reads f32 ONCE at streaming BW. Fusing the
// conversion into the consumers lost twice (r15 qkv: latency-bound panel
// re-fetch; r16 relk: scattered loads on the serial prologue path, +10 µs).
// ---------------------------------------------------------------------------
__global__ __launch_bounds__(256) void cvt_all_kernel(
    const float* x0, const float* x1, const float* x2, const float* w0,
    const float* w1, const float* w2, const float* w3, const float* relk,
    u16* y0, u16* y1, u16* y2, u16* z0, u16* z1, u16* z2, u16* z3,
    u16* relkb) {
  const int z = blockIdx.z;
  if (z == 7) {
    // relk [33][64] f32 -> relkb [64][64] bf16 (rows 33..63 zero)
    const int i = (blockIdx.x * 256 + threadIdx.x) * 8;
    if (i < 4096) {
      if (i < 2112) {
        const float4 a = *(const float4*)(relk + i);
        const float4 b = *(const float4*)(relk + i + 4);
        unsigned int o[4];
        o[0] = f2us2(a.x, a.y); o[1] = f2us2(a.z, a.w);
        o[2] = f2us2(b.x, b.y); o[3] = f2us2(b.z, b.w);
        *(uint4*)(relkb + i) = *(uint4*)o;
      } else {
        uint4 zz = {0u, 0u, 0u, 0u};
        *(uint4*)(relkb + i) = zz;
      }
    }
    return;
  }
  const float* src; u16* dst; int n;
  switch (z) {
    case 0: src = x0; dst = y0; n = 4194304; break;
    case 1: src = x1; dst = y1; n = 4194304; break;
    case 2: src = x2; dst = y2; n = 4194304; break;
    case 3: src = w0; dst = z0; n = 1048576; break;
    case 4: src = w1; dst = z1; n = 1048576; break;
    case 5: src = w2; dst = z2; n = 1048576; break;
    default: src = w3; dst = z3; n = 1048576; break;
  }
  const int i = (blockIdx.x * 256 + threadIdx.x) * 8;
  if (i < n) {
    const float4 a = *(const float4*)(src + i);
    const float4 b = *(const float4*)(src + i + 4);
    unsigned int o[4];
    o[0] = f2us2(a.x, a.y); o[1] = f2us2(a.z, a.w);
    o[2] = f2us2(b.x, b.y); o[3] = f2us2(b.z, b.w);
    *(uint4*)(dst + i) = *(uint4*)o;
  }
}

// ---------------------------------------------------------------------------
// GEMM: Y = (X @ W^T + bias) * oscale.  BM x BN block tile, 4 waves (2x2),
// BK-deep K-steps (BK=64 or 128). BK=64 path byte-identical to verified r12.
// MODE 0: f32 row-major [4096][1024].  MODE 1: u16 [bh][s][d].  MODE 2:
// u16 [bh][d][s].  Modes 1/2 (BM=BN=128, BK=64 only) use an LDS transpose.
// ---------------------------------------------------------------------------
template <int MODE, typename OUT, int BM, int BN, int BK>
__device__ __forceinline__ void gemm_body(u16* __restrict__ SM,
                                          const u16* __restrict__ X,
                                          const u16* __restrict__ W,
                                          const float* __restrict__ bias,
                                          OUT* __restrict__ Y, int row0, int col0,
                                          float oscale) {
  constexpr int TM = BM / 32, TN = BN / 32;  // 16-row tiles per wave
  constexpr int CH = BK / 8;                 // 16B chunks per row
  constexpr int RPG = 64 / CH;               // rows per gload instruction
  constexpr int NGA = BM / (4 * RPG);        // A gloads per wave per k-step
  constexpr int NGB = BN / (4 * RPG);        // B gloads per wave per k-step
  u16* As = SM;              // [BM][BK]
  u16* Bs = SM + BM * BK;    // [BN][BK]
  const int tid = threadIdx.x;
  const int lane = tid & 63;
  const int wid = tid >> 6;
  const int wm = wid >> 1, wn = wid & 1;
  const int l15 = lane & 15, l16 = lane >> 4;
  const int lrow = lane / CH;   // row within gload group
  const int lch = lane % CH;    // chunk within row

  f32x4 acc[TM][TN];
#pragma unroll
  for (int i = 0; i < TM; i++)
#pragma unroll
    for (int j = 0; j < TN; j++) acc[i][j] = (f32x4){0.f, 0.f, 0.f, 0.f};

  for (int k0 = 0; k0 < 1024; k0 += BK) {
#pragma unroll
    for (int i = 0; i < NGA; i++) {
      const int rb = (wid * NGA + i) * RPG;
      const int row = rb + lrow;
      GLOAD_LDS16(X + (size_t)(row0 + row) * 1024 + k0 + ((lch ^ (row & 7)) * 8),
                  &As[rb * BK]);
    }
#pragma unroll
    for (int i = 0; i < NGB; i++) {
      const int rb = (wid * NGB + i) * RPG;
      const int row = rb + lrow;
      GLOAD_LDS16(W + (size_t)(col0 + row) * 1024 + k0 + ((lch ^ (row & 7)) * 8),
                  &Bs[rb * BK]);
    }
    __syncthreads();
#pragma unroll
    for (int kk = 0; kk < BK / 32; kk++) {
      const int ch = kk * 4 + l16;
      short8 af[TM], bfr[TN];
#pragma unroll
      for (int t = 0; t < TM; t++) {
        const int m = wm * (BM / 2) + t * 16 + l15;
        af[t] = *(const short8*)&As[m * BK + ((ch ^ (m & 7)) * 8)];
      }
#pragma unroll
      for (int t = 0; t < TN; t++) {
        const int n = wn * (BN / 2) + t * 16 + l15;
        bfr[t] = *(const short8*)&Bs[n * BK + ((ch ^ (n & 7)) * 8)];
      }
#pragma unroll
      for (int tm = 0; tm < TM; tm++)
#pragma unroll
        for (int tn = 0; tn < TN; tn++)
          acc[tm][tn] = MFMA16(af[tm], bfr[tn], acc[tm][tn]);
    }
    __syncthreads();
  }

  if (MODE == 0) {
#pragma unroll
    for (int tn = 0; tn < TN; tn++) {
      const int col = col0 + wn * (BN / 2) + tn * 16 + l15;
      const float bv = bias[col];
#pragma unroll
      for (int tm = 0; tm < TM; tm++) {
        const int rowb = row0 + wm * (BM / 2) + tm * 16 + l16 * 4;
#pragma unroll
        for (int r = 0; r < 4; r++)
          Y[(size_t)(rowb + r) * 1024 + col] = (OUT)(acc[tm][tn][r] + bv);
      }
    }
  } else {
    // LDS-transpose epilogue (BM=BN=128 only), two 64-row passes.
    u16* T = SM;
    const int bb = row0 >> 11;
    const int sbase = row0 & 2047;
#pragma unroll
    for (int pass = 0; pass < 2; pass++) {
      __syncthreads();
      if (wm == pass) {
#pragma unroll
        for (int tn = 0; tn < TN; tn++) {
          const int coll = wn * 64 + tn * 16 + l15;
          const float bv = bias[col0 + coll];
#pragma unroll
          for (int tm = 0; tm < TM; tm++) {
            if (MODE == 1) {
#pragma unroll
              for (int r = 0; r < 4; r++)
                T[(tm * 16 + l16 * 4 + r) * 136 + coll] = f2us((acc[tm][tn][r] + bv) * oscale);
            } else {
              unsigned int o[2];
              o[0] = f2us2(acc[tm][tn][0] + bv, acc[tm][tn][1] + bv);
              o[1] = f2us2(acc[tm][tn][2] + bv, acc[tm][tn][3] + bv);
              *(short4_t*)&T[coll * 72 + tm * 16 + l16 * 4] = *(short4_t*)o;
            }
          }
        }
      }
      __syncthreads();
      if (MODE == 1) {
#pragma unroll
        for (int i = 0; i < 8; i++) {
          const int idx = tid + i * 256;           // 2048 chunks of 4 u16
          const int srow = idx >> 5, c4 = idx & 31;
          const short4_t v = *(const short4_t*)&T[srow * 136 + c4 * 4];
          const int col = col0 + c4 * 4;
          const int hh = col >> 6, dd = col & 63;
          const int s = sbase + pass * 64 + srow;
          *(short4_t*)&((u16*)Y)[(((size_t)(bb * 16 + hh)) * 2048 + s) * 64 + dd] = v;
        }
      } else {
#pragma unroll
        for (int i = 0; i < 4; i++) {
          const int idx = tid + i * 256;           // 1024 chunks of 8 u16
          const int cl = idx >> 3, sc = idx & 7;
          const short8 v = *(const short8*)&T[cl * 72 + sc * 8];
          const int col = col0 + cl;
          const int hh = col >> 6, dd = col & 63;
          const int s = sbase + pass * 64 + sc * 8;
          *(short8*)&((u16*)Y)[(((size_t)(bb * 16 + hh)) * 64 + dd) * 2048 + s] = v;
        }
      }
    }
  }
}

__global__ __launch_bounds__(256) void qkv_kernel(
    const u16* Xq, const u16* Xk, const u16* Xv, const u16* Wq, const u16* Wk,
    const u16* Wv, const float* bq, const float* bk, const float* bv, u16* Yq,
    u16* Yk, u16* Yv) {
  __shared__ __align__(16) u16 SM[16384];
  const int z = blockIdx.z;
  const u16* X = z == 0 ? Xq : (z == 1 ? Xk : Xv);
  const u16* W = z == 0 ? Wq : (z == 1 ? Wk : Wv);
  const float* bi = z == 0 ? bq : (z == 1 ? bk : bv);
  u16* Y = z == 0 ? Yq : (z == 1 ? Yk : Yv);
  if (z == 2)
    gemm_body<2, u16, 128, 128, 64>(SM, X, W, bi, Y, blockIdx.x * 128,
                                    blockIdx.y * 128, 1.0f);
  else
    gemm_body<1, u16, 128, 128, 64>(SM, X, W, bi, Y, blockIdx.x * 128,
                                    blockIdx.y * 128,
                                    z == 0 ? LOG2E : 1.0f);  // fold 1/ln2 into Q
}

// oproj: 64x64 tiles (1024 blocks = 4/CU), BK=128 (r18: halves sync points).
__global__ __launch_bounds__(256) void oproj_kernel(const u16* Xc, const u16* Wo,
                                                    const float* bo, float* out) {
  __shared__ __align__(16) u16 SM[16384];
  gemm_body<0, float, 64, 64, 128>(SM, Xc, Wo, bo, out, blockIdx.x * 64,
                                   blockIdx.y * 64, 1.0f);
}

// ---------------------------------------------------------------------------
// Flash attention (S^T trick, rel-pos). r20 = r19 (2 q-tiles/block, 8 waves)
// + KVBLK=128 staging: two 64-wide K/V sub-tiles staged per sync event as
// four independent 8 KB tiles (K0,K1,V0,V1 — same lane pattern + XOR swizzle
// as the verified 64-tile staging, different LDS offsets). 16 vmcnt(0)
// drains + barrier pairs instead of 32; same gload/MFMA counts, same K-order
// (bit-identical results). Compute runs the r19 64-tile body twice with a
// base-pointer switch; classification granularity stays 64.
// ---------------------------------------------------------------------------
__global__ __launch_bounds__(512, 4) void attn_kernel(
    const u16* __restrict__ Qg, const u16* __restrict__ Kg,
    const u16* __restrict__ Vtg, const u16* __restrict__ relkb,
    const float* __restrict__ relv, u16* __restrict__ ctx) {
  // K0 [0,4096), K1 [4096,8192), V0 [8192,12288), V1 [12288,16384) (u16 idx)
  __shared__ __align__(16) u16 KV[16384];
  __shared__ __align__(16) u16 qrelJ[128 * 33]; // Q[q]·relk[j] bf16
  __shared__ __align__(16) u16 wsum[128 * 32];  // in-band p, write-once, col31=0

  const int tid = threadIdx.x, lane = tid & 63, wid = tid >> 6;  // wid 0..7
  const int l15 = lane & 15, l16 = lane >> 4;
  const int bh = blockIdx.x;  // x-fast => all q-tiles of a bh land on one XCD
  const int b = bh >> 4, h = bh & 15;
  const int by = blockIdx.y;            // 0..15
  const int q0b = by * 128;             // block q base (128 rows)
  const int qt = wid >> 2;              // q-tile 0/1 within block
  const int q0w = q0b + qt * 64;        // wave's q-tile base (classification)
  const u16* Qb = Qg + (size_t)bh * 2048 * 64;
  const u16* Kb = Kg + (size_t)bh * 2048 * 64;
  const u16* Vtb = Vtg + (size_t)bh * 64 * 2048;  // [d][s]

  const int lrow = lane >> 3;
  const int lchunk = (lane & 7) ^ lrow;
  const int qw16 = wid * 16;            // row base in 128-row block space
  const int kq4 = l16 * 4;
  const int qrow = qw16 + l15;          // 0..127

  // ---- prologue: stage 128 Q rows into KV, zero wsum ----
#pragma unroll
  for (int i = 0; i < 2; i++) {
    const int rb = qw16 + i * 8;
    GLOAD_LDS16(Qb + (size_t)(q0b + rb + lrow) * 64 + lchunk * 8, &KV[rb * 64]);
  }
  for (int idx = tid; idx < 2048; idx += 512) ((unsigned int*)wsum)[idx] = 0u;
  __syncthreads();

  // ---- hoist Q fragment (wave's 16 rows of the 128-row staging) ----
  short8 aq[2];
  {
    const int m = qrow;
    aq[0] = *(const short8*)&KV[m * 64 + ((l16 ^ (m & 7)) * 8)];
    aq[1] = *(const short8*)&KV[m * 64 + (((4 + l16) ^ (m & 7)) * 8)];
  }
  // ---- qrel GEMM: qrelJ[q][j] = Q[q]·relk[j] ----
  {
    f32x4 qa[3];
#pragma unroll
    for (int nt = 0; nt < 3; nt++) {
      qa[nt] = (f32x4){0.f, 0.f, 0.f, 0.f};
#pragma unroll
      for (int kk = 0; kk < 2; kk++) {
        const short8 bf =
            *(const short8*)(relkb + (nt * 16 + l15) * 64 + kk * 32 + l16 * 8);
        qa[nt] = MFMA16(aq[kk], bf, qa[nt]);
      }
    }
#pragma unroll
    for (int nt = 0; nt < 3; nt++) {
      if (nt < 2 || l15 == 0) {
#pragma unroll
        for (int r = 0; r < 4; r++)
          qrelJ[(qw16 + kq4 + r) * 33 + nt * 16 + l15] = f2us(qa[nt][r]);
      }
    }
  }
  WAIT_LGKM0();  // aq reads + qrelJ writes drained before KV overwrite / reads
  const float q0r = us2f(qrelJ[qrow * 33 + 0]);
  const float q32r = us2f(qrelJ[qrow * 33 + 32]);
  const f32x4 ebl = (f32x4){q0r, q0r, q0r, q0r};
  const f32x4 ebr = (f32x4){q32r, q32r, q32r, q32r};
  const f32x4 zf = (f32x4){0.f, 0.f, 0.f, 0.f};
  const short4_t ones4 = (short4_t){(short)0x3F80, (short)0x3F80,
                                    (short)0x3F80, (short)0x3F80};

  float wl_p = 0.f, wr_p = 0.f;            // diag-tile partials (VALU)
  f32x4 SL = zf, SR = zf, SD = zf;         // ones-MFMA denominator sums
  f32x4 Oacc[4];
#pragma unroll
  for (int t = 0; t < 4; t++) Oacc[t] = zf;

  // S^T quadrant tn = K·Q^T with C-init (bias pre-folded for off-diag)
  auto qk = [&](const u16* Ks, int tn, f32x4 cin) -> f32x4 {
    const int n = tn * 16 + l15;
    const short8 bk0 = *(const short8*)&Ks[n * 64 + ((l16 ^ (n & 7)) * 8)];
    const short8 bk1 = *(const short8*)&Ks[n * 64 + (((4 + l16) ^ (n & 7)) * 8)];
    f32x4 s = MFMA16(bk0, aq[0], cin);
    s = MFMA16(bk1, aq[1], s);
    return s;
  };

  // O^T += V^T · P^T
  auto pvstep = [&](const u16* Vs, const short4_t* pf) {
    __builtin_amdgcn_s_setprio(1);
#pragma unroll
    for (int td = 0; td < 4; td++) {
      const int row = td * 16 + l15;
      const int rs = row & 7;
#pragma unroll
      for (int kk = 0; kk < 4; kk++) {
        const short4_t vf = *(const short4_t*)&Vs[row * 64 +
                                                  (((kk * 2 + (l16 >> 1)) ^ rs) * 8) +
                                                  (l16 & 1) * 4];
        Oacc[td] = MFMAK16(vf, pf[kk], Oacc[td]);
      }
    }
    __builtin_amdgcn_s_setprio(0);
  };

  // denominator: S += colsum(P) via ones-row MFMA (matrix pipe, no VALU)
  auto psum = [&](const short4_t* pf, f32x4& S) {
#pragma unroll
    for (int kk = 0; kk < 4; kk++) S = MFMAK16(ones4, pf[kk], S);
  };

  // off-diagonal tile body: bias folded into C, no per-score bookkeeping
  auto offdiag = [&](const u16* Ks, const u16* Vs, f32x4 ebv, f32x4& S) {
    short4_t pf[4];
#pragma unroll
    for (int tn = 0; tn < 4; tn++) {
      const f32x4 sac = qk(Ks, tn, ebv);
      union { unsigned int u[2]; short4_t s; } c;
      c.u[0] = f2us2(exp2fast(sac[0]), exp2fast(sac[1]));
      c.u[1] = f2us2(exp2fast(sac[2]), exp2fast(sac[3]));
      pf[tn] = c.s;
    }
    pvstep(Vs, pf);
    psum(pf, S);
  };

  // diagonal tile body: per-element clamp/bias, in-band p to wsum
  auto diag = [&](const u16* Ks, const u16* Vs, int k0) {
    short4_t pf[4];
#pragma unroll
    for (int tn = 0; tn < 4; tn++) {
      const f32x4 sac = qk(Ks, tn, zf);
      float pv4[4];
#pragma unroll
      for (int r = 0; r < 4; r++) {
        const int kg = k0 + tn * 16 + kq4 + r;
        const int dlt = kg - (q0b + qrow);
        const int jj = (dlt < -16 ? -16 : (dlt > 16 ? 16 : dlt)) + 16;
        const float p = exp2fast(sac[r] + us2f(qrelJ[qrow * 33 + jj]));
        pv4[r] = p;
        if (dlt <= -16) wl_p += p;
        else if (dlt >= 16) wr_p += p;
        else wsum[qrow * 32 + (dlt + 15)] = f2us(p);
      }
      union { unsigned int u[2]; short4_t s; } c;
      c.u[0] = f2us2(pv4[0], pv4[1]);
      c.u[1] = f2us2(pv4[2], pv4[3]);
      pf[tn] = c.s;
    }
    pvstep(Vs, pf);
    psum(pf, SD);
  };

  // ---- main loop: 16 staging events of 128 K/V rows (2 x 64-wide halves) ----
  for (int kt2 = 0; kt2 < 16; ++kt2) {
    const int k0 = kt2 * 128;
    SBAR();  // all waves done reading previous tiles
    {
      const int rb = wid * 8;
      GLOAD_LDS16(Kb + (size_t)(k0 + rb + lrow) * 64 + lchunk * 8, &KV[rb * 64]);
      GLOAD_LDS16(Kb + (size_t)(k0 + 64 + rb + lrow) * 64 + lchunk * 8,
                  &KV[4096 + rb * 64]);
      GLOAD_LDS16(Vtb + (size_t)(rb + lrow) * 2048 + k0 + lchunk * 8,
                  &KV[8192 + rb * 64]);
      GLOAD_LDS16(Vtb + (size_t)(rb + lrow) * 2048 + k0 + 64 + lchunk * 8,
                  &KV[12288 + rb * 64]);
    }
    WAIT_VM0();
    SBAR();  // both halves visible to all waves
#pragma unroll
    for (int hh2 = 0; hh2 < 2; ++hh2) {
      const int kh = k0 + hh2 * 64;
      const u16* Ks = &KV[hh2 * 4096];
      const u16* Vs = &KV[8192 + hh2 * 4096];
      if (kh + 79 <= q0w) {
        offdiag(Ks, Vs, ebl, SL);
      } else if (kh >= q0w + 79) {
        offdiag(Ks, Vs, ebr, SR);
      } else {
        diag(Ks, Vs, kh);
      }
    }
  }

  // ---- epilogue ----
  wl_p += __shfl_xor(wl_p, 16); wl_p += __shfl_xor(wl_p, 32);
  wr_p += __shfl_xor(wr_p, 16); wr_p += __shfl_xor(wr_p, 32);
  const float l_total = SL[0] + SR[0] + SD[0];   // full col sums, no shuffle
  const float linv = 1.f / l_total;
  const float wl = (SL[0] + wl_p) * linv;
  const float wr = (SR[0] + wr_p) * linv;

  // rel_v in-band term as a matmul: O^T[d][q] += sum_c relv[c+1][d]*wsum[q][c]
  {
    short4_t relf[4][2];  // A: rows d=td*16+l15, k = kk*16 + l16*4 + e
#pragma unroll
    for (int td = 0; td < 4; td++)
#pragma unroll
      for (int kk = 0; kk < 2; kk++) {
        const int jb = kk * 16 + l16 * 4 + 1;  // relv rows 1..32, all valid
        const int d = td * 16 + l15;
        union { unsigned int u[2]; short4_t s; } c;
        c.u[0] = f2us2(relv[(jb + 0) * 64 + d], relv[(jb + 1) * 64 + d]);
        c.u[1] = f2us2(relv[(jb + 2) * 64 + d], relv[(jb + 3) * 64 + d]);
        relf[td][kk] = c.s;
      }
    WAIT_LGKM0();  // wave's own wsum ds_writes drained before re-read
    short4_t wfrag[2];    // B: col q=qrow, k = kk*16 + l16*4 + e (col31=0)
#pragma unroll
    for (int kk = 0; kk < 2; kk++)
      wfrag[kk] = *(const short4_t*)&wsum[qrow * 32 + kk * 16 + l16 * 4];
#pragma unroll
    for (int td = 0; td < 4; td++)
#pragma unroll
      for (int kk = 0; kk < 2; kk++)
        Oacc[td] = MFMAK16(relf[td][kk], wfrag[kk], Oacc[td]);
  }

#pragma unroll
  for (int td = 0; td < 4; td++) {
    const f32x4 rv0 = *(const f32x4*)&relv[td * 16 + kq4];
    const f32x4 rv32 = *(const f32x4*)&relv[32 * 64 + td * 16 + kq4];
#pragma unroll
    for (int r = 0; r < 4; r++)
      Oacc[td][r] = Oacc[td][r] * linv + wl * rv0[r] + wr * rv32[r];
  }

  SBAR();  // all waves past their last KV reads -> KV free for O tile
  // O store: two 64-row passes through KV ([64][72] u16, b128-aligned)
#pragma unroll
  for (int pass = 0; pass < 2; pass++) {
    if (qt == pass) {
      const int orow = (wid & 3) * 16 + l15;  // 0..63 within this q-tile
#pragma unroll
      for (int td = 0; td < 4; td++) {
        unsigned int o[2];
        o[0] = f2us2(Oacc[td][0], Oacc[td][1]);
        o[1] = f2us2(Oacc[td][2], Oacc[td][3]);
        *(short4_t*)&KV[orow * 72 + td * 16 + kq4] = *(short4_t*)o;
      }
      WAIT_LGKM0();
    }
    SBAR();
    {
      const int q = tid >> 3, sc = tid & 7;  // 512 chunks of 8 u16
      const short8 v = *(const short8*)&KV[q * 72 + sc * 8];
      *(short8*)&ctx[((size_t)b * 2048 + q0b + pass * 64 + q) * 1024 + h * 64 +
                     sc * 8] = v;
    }
    SBAR();  // reads done before next pass overwrites KV
  }
}

// ---------------------------------------------------------------------------
extern "C" void kernel_launch(void* const* d_in, const int* in_sizes, int n_in,
                              void* d_out, int out_size, void* d_ws, size_t ws_size,
                              hipStream_t stream) {
  u16* qb = (u16*)d_ws;                 // [32][2048][64]
  u16* kb = qb + 4194304;               // [32][2048][64]
  u16* vtb = kb + 4194304;              // [32][64][2048]
  u16* ctx = vtb + 4194304;             // [2][2048][1024]
  u16* Xq = ctx + 4194304;
  u16* Xk = Xq + 4194304;
  u16* Xv = Xk + 4194304;
  u16* Wqb = Xv + 4194304;
  u16* Wkb = Wqb + 1048576;
  u16* Wvb = Wkb + 1048576;
  u16* Wob = Wvb + 1048576;
  u16* relkb = Wob + 1048576;           // [64][64] bf16

  const float* bq = (const float*)d_in[4];
  const float* bk = (const float*)d_in[6];
  const float* bv = (const float*)d_in[8];
  const float* bo = (const float*)d_in[10];
  const float* relk = (const float*)d_in[11];
  const float* relv = (const float*)d_in[12];

  dim3 blk(256);
  cvt_all_kernel<<<dim3(2048, 1, 8), blk, 0, stream>>>(
      (const float*)d_in[0], (const float*)d_in[1], (const float*)d_in[2],
      (const float*)d_in[3], (const float*)d_in[5], (const float*)d_in[7],
      (const float*)d_in[9], relk, Xq, Xk, Xv, Wqb, Wkb, Wvb, Wob, relkb);
  qkv_kernel<<<dim3(32, 8, 3), blk, 0, stream>>>(Xq, Xk, Xv, Wqb, Wkb, Wvb, bq,
                                                 bk, bv, qb, kb, vtb);
  attn_kernel<<<dim3(32, 16), dim3(512), 0, stream>>>(qb, kb, vtb, relkb, relv,
                                                      ctx);
  oproj_kernel<<<dim3(64, 16), blk, 0, stream>>>(ctx, Wob, bo, (float*)d_out);
}